// Round 1
// baseline (236.686 us; speedup 1.0000x reference)
//
#include <hip/hip_runtime.h>

#define NHEADS 32
#define HD_ 32
#define TSEQ 2048
#define SCALE_ 0.12f
#define RMS_EPS_ 1.1920929e-07f

typedef unsigned short ushort_t;
typedef __bf16 bf16_t;
typedef __attribute__((ext_vector_type(8))) bf16_t bf16x8;
typedef __attribute__((ext_vector_type(4))) float f32x4;
typedef __attribute__((ext_vector_type(8))) unsigned short u16x8;

__device__ __forceinline__ ushort_t f2bf(float f){
    union { float f; unsigned u; } v; v.f = f;
    return (ushort_t)((v.u + 0x7fffu + ((v.u >> 16) & 1u)) >> 16);
}
__device__ __forceinline__ float bf2f(ushort_t s){
    union { unsigned u; float f; } v; v.u = ((unsigned)s) << 16;
    return v.f;
}

// ---------------- fp32 -> bf16 convert ----------------
__global__ __launch_bounds__(256) void k_convert(const float* __restrict__ src,
                                                 ushort_t* __restrict__ dst, int n4){
    int i = blockIdx.x * blockDim.x + threadIdx.x;
    int stride = gridDim.x * blockDim.x;
    for (; i < n4; i += stride){
        float4 v = ((const float4*)src)[i];
        ushort4 o;
        o.x = f2bf(v.x); o.y = f2bf(v.y); o.z = f2bf(v.z); o.w = f2bf(v.w);
        ((ushort4*)dst)[i] = o;
    }
}

// ---------------- rotary tables: cos/sin (T x 16) ----------------
__global__ __launch_bounds__(256) void k_tables(float* __restrict__ cost, float* __restrict__ sint){
    int gid = blockIdx.x * 256 + threadIdx.x;
    if (gid >= TSEQ * 16) return;
    int t = gid >> 4, i = gid & 15;
    float c = 1.0f, s = 0.0f;
    if (i < 8){
        float af = powf(1.0f / 128.0f, (float)i * (1.0f / 7.0f)); // = 2^-i
        float th = (float)t * af;
        sincosf(th, &s, &c);
    }
    cost[gid] = c;
    sint[gid] = s;
}

// ---------------- bf16 GEMM: C[M,N] = A[M,K] * B[N,K]^T ----------------
// 128x128 tile, 4 waves (2x2), each wave 64x64 = 4x4 fragments of 16x16x32 MFMA.
template<bool OUT_BF16>
__global__ __launch_bounds__(256) void k_gemm_bt(const ushort_t* __restrict__ A,
                                                 const ushort_t* __restrict__ B,
                                                 void* __restrict__ C,
                                                 int M, int N, int K)
{
    __shared__ __align__(16) ushort_t As[128 * 40]; // +8 pad: 2-way bank conflicts only
    __shared__ __align__(16) ushort_t Bs[128 * 40];
    const int tid = threadIdx.x;
    const int lane = tid & 63;
    const int w = tid >> 6;
    const int wr = w >> 1, wc = w & 1;
    const int l15 = lane & 15, hi = lane >> 4;
    const int m0 = blockIdx.y * 128, n0 = blockIdx.x * 128;

    f32x4 acc[4][4] = {};

    for (int k0 = 0; k0 < K; k0 += 32){
        __syncthreads();
        #pragma unroll
        for (int i = 0; i < 2; ++i){
            int c = tid + i * 256;          // 512 chunks of 8 elems (16B)
            int row = c >> 2, kc = (c & 3) * 8;
            *(u16x8*)&As[row * 40 + kc] = *(const u16x8*)&A[(size_t)(m0 + row) * K + k0 + kc];
            *(u16x8*)&Bs[row * 40 + kc] = *(const u16x8*)&B[(size_t)(n0 + row) * K + k0 + kc];
        }
        __syncthreads();
        bf16x8 af[4], bfr[4];
        #pragma unroll
        for (int mi = 0; mi < 4; ++mi)
            af[mi] = *(const bf16x8*)&As[(wr * 64 + mi * 16 + l15) * 40 + hi * 8];
        #pragma unroll
        for (int ni = 0; ni < 4; ++ni)
            bfr[ni] = *(const bf16x8*)&Bs[(wc * 64 + ni * 16 + l15) * 40 + hi * 8];
        #pragma unroll
        for (int mi = 0; mi < 4; ++mi)
            #pragma unroll
            for (int ni = 0; ni < 4; ++ni)
                acc[mi][ni] = __builtin_amdgcn_mfma_f32_16x16x32_bf16(af[mi], bfr[ni], acc[mi][ni], 0, 0, 0);
    }

    #pragma unroll
    for (int mi = 0; mi < 4; ++mi){
        #pragma unroll
        for (int ni = 0; ni < 4; ++ni){
            #pragma unroll
            for (int r = 0; r < 4; ++r){
                int row = m0 + wr * 64 + mi * 16 + hi * 4 + r;
                int col = n0 + wc * 64 + ni * 16 + l15;
                float v = acc[mi][ni][r];
                if (OUT_BF16) ((ushort_t*)C)[(size_t)row * N + col] = f2bf(v);
                else          ((float*)C)[(size_t)row * N + col] = v;
            }
        }
    }
}

// ---------------- fuse: RMSNorm + rotary (+SCALE into q), v = l0*v + l1*ve, transpose v ----------------
// grid (TSEQ/64, NHEADS), block 256. thread: tl = tid>>2 (t within tile), dg = tid&3 (8 dims each).
__global__ __launch_bounds__(256) void k_fuse(const ushort_t* __restrict__ qkvb,
                                              const float* __restrict__ ve,
                                              const float* __restrict__ lam,
                                              const float* __restrict__ cost,
                                              const float* __restrict__ sint,
                                              ushort_t* __restrict__ qb,
                                              ushort_t* __restrict__ kb,
                                              ushort_t* __restrict__ vtb)
{
    const int h  = blockIdx.y;
    const int t0 = blockIdx.x * 64;
    const int tid = threadIdx.x;
    const int tl = tid >> 2;
    const int dg = tid & 3;
    const int t  = t0 + tl;

    __shared__ __align__(16) float vtile[32 * 65];

    float cs[8], sn[8];
    #pragma unroll
    for (int j = 0; j < 8; ++j){
        int ci = (dg * 8 + j) & 15;
        cs[j] = cost[t * 16 + ci];
        sn[j] = sint[t * 16 + ci];
    }
    const float sgn = (dg < 2) ? 1.0f : -1.0f;   // x1 half: +p*s ; x2 half: -p*s

    #pragma unroll
    for (int which = 0; which < 2; ++which){     // 0 = q, 1 = k
        u16x8 raw = *(const u16x8*)&qkvb[(size_t)t * 3072 + which * 1024 + h * 32 + dg * 8];
        float v[8];
        float ss = 0.0f;
        #pragma unroll
        for (int j = 0; j < 8; ++j){ v[j] = bf2f(raw[j]); ss += v[j] * v[j]; }
        ss += __shfl_xor(ss, 1);
        ss += __shfl_xor(ss, 2);                 // sum of squares over 32 dims (4-lane group)
        const float inv = rsqrtf(ss * (1.0f / 32.0f) + RMS_EPS_);
        const float scl = (which == 0) ? SCALE_ : 1.0f;
        u16x8 o;
        #pragma unroll
        for (int j = 0; j < 8; ++j){
            float nv = v[j] * inv;
            float p  = __shfl_xor(nv, 2);        // partner dim (d ^ 16)
            o[j] = f2bf((nv * cs[j] + sgn * p * sn[j]) * scl);
        }
        ushort_t* dst = (which == 0) ? qb : kb;
        *(u16x8*)&dst[((size_t)h * TSEQ + t) * 32 + dg * 8] = o;
    }

    // v mix + transpose to vtb[h][d][t]
    const float l0 = lam[0], l1 = lam[1];
    {
        u16x8 raw = *(const u16x8*)&qkvb[(size_t)t * 3072 + 2048 + h * 32 + dg * 8];
        const float4* vep = (const float4*)&ve[(size_t)t * 1024 + h * 32 + dg * 8];
        float4 a = vep[0], b = vep[1];
        float vef[8] = {a.x, a.y, a.z, a.w, b.x, b.y, b.z, b.w};
        #pragma unroll
        for (int j = 0; j < 8; ++j)
            vtile[(dg * 8 + j) * 65 + tl] = l0 * bf2f(raw[j]) + l1 * vef[j];
    }
    __syncthreads();
    {
        const int d = tid >> 3, jj = tid & 7;
        u16x8 o;
        #pragma unroll
        for (int e = 0; e < 8; ++e)
            o[e] = f2bf(vtile[d * 65 + jj * 8 + e]);
        *(u16x8*)&vtb[((size_t)h * HD_ + d) * TSEQ + t0 + jj * 8] = o;
    }
}

// ---------------- causal flash attention ----------------
// grid (TSEQ/64, NHEADS), block 256 = 4 waves; wave w owns q rows [q0+16w, q0+16w+16).
__global__ __launch_bounds__(256) void k_attn(const ushort_t* __restrict__ qb,
                                              const ushort_t* __restrict__ kb,
                                              const ushort_t* __restrict__ vtb,
                                              ushort_t* __restrict__ yb)
{
    const int h  = blockIdx.y;
    const int q0 = blockIdx.x * 64;
    const int tid = threadIdx.x;
    const int w = tid >> 6, lane = tid & 63;
    const int l15 = lane & 15, hi = lane >> 4;
    const int qw = q0 + w * 16;

    __shared__ __align__(16) ushort_t Pbuf[4][16 * 72];  // per-wave, stride 72 (2-way conflicts)
    ushort_t* pb = &Pbuf[w][0];

    const bf16x8 q_frag = *(const bf16x8*)&qb[((size_t)h * TSEQ + qw + l15) * 32 + hi * 8];

    f32x4 acc0 = {0.f, 0.f, 0.f, 0.f}, acc1 = {0.f, 0.f, 0.f, 0.f};
    float m[4]    = {-1e30f, -1e30f, -1e30f, -1e30f};
    float lsum[4] = {0.f, 0.f, 0.f, 0.f};

    const int ntiles = (qw + 79) >> 6;   // cover keys < qw+16 (causal)
    for (int kt = 0; kt < ntiles; ++kt){
        const int kb0 = kt * 64;
        f32x4 s[4];
        #pragma unroll
        for (int ni = 0; ni < 4; ++ni){
            bf16x8 kf = *(const bf16x8*)&kb[((size_t)h * TSEQ + kb0 + ni * 16 + l15) * 32 + hi * 8];
            f32x4 z = {0.f, 0.f, 0.f, 0.f};
            s[ni] = __builtin_amdgcn_mfma_f32_16x16x32_bf16(q_frag, kf, z, 0, 0, 0);
        }
        // causal mask (scores pre-scaled: SCALE folded into q)
        #pragma unroll
        for (int ni = 0; ni < 4; ++ni){
            int col = kb0 + ni * 16 + l15;
            #pragma unroll
            for (int r = 0; r < 4; ++r){
                int row = qw + hi * 4 + r;
                if (col > row) s[ni][r] = -1e30f;
            }
        }
        // online softmax (row r lives in lanes of same hi-group)
        float sc[4];
        #pragma unroll
        for (int r = 0; r < 4; ++r){
            float mt = fmaxf(fmaxf(s[0][r], s[1][r]), fmaxf(s[2][r], s[3][r]));
            mt = fmaxf(mt, __shfl_xor(mt, 1));
            mt = fmaxf(mt, __shfl_xor(mt, 2));
            mt = fmaxf(mt, __shfl_xor(mt, 4));
            mt = fmaxf(mt, __shfl_xor(mt, 8));
            float mn = fmaxf(m[r], mt);
            sc[r] = __expf(m[r] - mn);
            m[r] = mn;
        }
        float rs[4] = {0.f, 0.f, 0.f, 0.f};
        #pragma unroll
        for (int ni = 0; ni < 4; ++ni){
            #pragma unroll
            for (int r = 0; r < 4; ++r){
                float p = __expf(s[ni][r] - m[r]);
                s[ni][r] = p;
                rs[r] += p;
            }
        }
        #pragma unroll
        for (int r = 0; r < 4; ++r){
            rs[r] += __shfl_xor(rs[r], 1);
            rs[r] += __shfl_xor(rs[r], 2);
            rs[r] += __shfl_xor(rs[r], 4);
            rs[r] += __shfl_xor(rs[r], 8);
            lsum[r] = lsum[r] * sc[r] + rs[r];
            acc0[r] *= sc[r];
            acc1[r] *= sc[r];
        }
        // P -> LDS (layout [qrow][key], row stride 72)
        #pragma unroll
        for (int ni = 0; ni < 4; ++ni)
            #pragma unroll
            for (int r = 0; r < 4; ++r)
                pb[(hi * 4 + r) * 72 + ni * 16 + l15] = f2bf(s[ni][r]);
        // PV: A = P (row=l15, k-contig), B = V^T (col=l15 is head dim, k-contig along t)
        #pragma unroll
        for (int kk = 0; kk < 2; ++kk){
            bf16x8 pf = *(const bf16x8*)&pb[l15 * 72 + kk * 32 + hi * 8];
            bf16x8 v0 = *(const bf16x8*)&vtb[((size_t)h * HD_ + l15) * TSEQ + kb0 + kk * 32 + hi * 8];
            bf16x8 v1 = *(const bf16x8*)&vtb[((size_t)h * HD_ + 16 + l15) * TSEQ + kb0 + kk * 32 + hi * 8];
            acc0 = __builtin_amdgcn_mfma_f32_16x16x32_bf16(pf, v0, acc0, 0, 0, 0);
            acc1 = __builtin_amdgcn_mfma_f32_16x16x32_bf16(pf, v1, acc1, 0, 0, 0);
        }
    }
    #pragma unroll
    for (int r = 0; r < 4; ++r){
        float inv = 1.0f / lsum[r];
        int row = qw + hi * 4 + r;
        yb[(size_t)row * 1024 + h * 32 + l15]      = f2bf(acc0[r] * inv);
        yb[(size_t)row * 1024 + h * 32 + 16 + l15] = f2bf(acc1[r] * inv);
    }
}

// ---------------- launcher ----------------
extern "C" void kernel_launch(void* const* d_in, const int* in_sizes, int n_in,
                              void* d_out, int out_size, void* d_ws, size_t ws_size,
                              hipStream_t stream)
{
    const float* x   = (const float*)d_in[0];
    const float* ve  = (const float*)d_in[1];
    const float* qkw = (const float*)d_in[2];
    const float* lam = (const float*)d_in[3];
    const float* cpw = (const float*)d_in[4];

    char* ws = (char*)d_ws;
    size_t o = 0;
    auto take = [&](size_t bytes) -> char* {
        char* p = ws + o; o += (bytes + 255) & ~(size_t)255; return p;
    };
    ushort_t* xb   = (ushort_t*)take((size_t)TSEQ * 1024 * 2);
    ushort_t* wb   = (ushort_t*)take((size_t)3072 * 1024 * 2);
    ushort_t* cpb  = (ushort_t*)take((size_t)1024 * 1024 * 2);
    ushort_t* qkvb = (ushort_t*)take((size_t)TSEQ * 3072 * 2);
    float*    cost = (float*)take((size_t)TSEQ * 16 * 4);
    float*    sint = (float*)take((size_t)TSEQ * 16 * 4);
    ushort_t* qb   = (ushort_t*)take((size_t)NHEADS * TSEQ * HD_ * 2);
    ushort_t* kb   = (ushort_t*)take((size_t)NHEADS * TSEQ * HD_ * 2);
    ushort_t* vtb  = (ushort_t*)take((size_t)NHEADS * HD_ * TSEQ * 2);
    ushort_t* yb   = xb;  // xb is dead after the QKV GEMM; reuse for y

    k_convert<<<512, 256, 0, stream>>>(x,   xb,  TSEQ * 1024 / 4);
    k_convert<<<768, 256, 0, stream>>>(qkw, wb,  3072 * 1024 / 4);
    k_convert<<<256, 256, 0, stream>>>(cpw, cpb, 1024 * 1024 / 4);
    k_tables<<<TSEQ * 16 / 256, 256, 0, stream>>>(cost, sint);
    k_gemm_bt<true ><<<dim3(3072 / 128, TSEQ / 128), 256, 0, stream>>>(xb, wb, qkvb, TSEQ, 3072, 1024);
    k_fuse<<<dim3(TSEQ / 64, NHEADS), 256, 0, stream>>>(qkvb, ve, lam, cost, sint, qb, kb, vtb);
    k_attn<<<dim3(TSEQ / 64, NHEADS), 256, 0, stream>>>(qb, kb, vtb, yb);
    k_gemm_bt<false><<<dim3(1024 / 128, TSEQ / 128), 256, 0, stream>>>(yb, cpb, (float*)d_out, TSEQ, 1024, 1024);
}

// Round 2
// 189.969 us; speedup vs baseline: 1.2459x; 1.2459x over previous
//
#include <hip/hip_runtime.h>
#include <hip/hip_bf16.h>

#define NHEADS 32
#define HD_ 32
#define TSEQ 2048
#define SCALE_ 0.12f
#define LOG2E_ 1.44269504088896f
#define RMS_EPS_ 1.1920929e-07f

typedef unsigned short ushort_t;
typedef __bf16 bf16_t;
typedef __attribute__((ext_vector_type(8))) bf16_t bf16x8;
typedef __attribute__((ext_vector_type(4))) float f32x4;
typedef __attribute__((ext_vector_type(8))) unsigned short u16x8;

__device__ __forceinline__ ushort_t f2bfn(float f){
    __hip_bfloat16 b = __float2bfloat16(f);
    return *reinterpret_cast<ushort_t*>(&b);
}
__device__ __forceinline__ float bf2f(ushort_t s){
    union { unsigned u; float f; } v; v.u = ((unsigned)s) << 16;
    return v.f;
}
__device__ __forceinline__ float fexp2(float x){
#if __has_builtin(__builtin_amdgcn_exp2f)
    return __builtin_amdgcn_exp2f(x);
#else
    return exp2f(x);
#endif
}
// async global->LDS, 16B per lane. LDS dest = wave-uniform base + lane*16 (HW adds lane offset).
__device__ __forceinline__ void gld16(const void* g, void* l){
    __builtin_amdgcn_global_load_lds(
        (const __attribute__((address_space(1))) unsigned int*)g,
        (__attribute__((address_space(3))) unsigned int*)l,
        16, 0, 0);
}

// ---------------- fp32 -> bf16 convert ----------------
__global__ __launch_bounds__(256) void k_convert(const float* __restrict__ src,
                                                 ushort_t* __restrict__ dst, int n4){
    int i = blockIdx.x * blockDim.x + threadIdx.x;
    int stride = gridDim.x * blockDim.x;
    for (; i < n4; i += stride){
        float4 v = ((const float4*)src)[i];
        ushort4 o;
        o.x = f2bfn(v.x); o.y = f2bfn(v.y); o.z = f2bfn(v.z); o.w = f2bfn(v.w);
        ((ushort4*)dst)[i] = o;
    }
}

// ---------------- rotary tables: cos/sin (T x 16) ----------------
__global__ __launch_bounds__(256) void k_tables(float* __restrict__ cost, float* __restrict__ sint){
    int gid = blockIdx.x * 256 + threadIdx.x;
    if (gid >= TSEQ * 16) return;
    int t = gid >> 4, i = gid & 15;
    float c = 1.0f, s = 0.0f;
    if (i < 8){
        float af = powf(1.0f / 128.0f, (float)i * (1.0f / 7.0f));
        float th = (float)t * af;
        sincosf(th, &s, &c);
    }
    cost[gid] = c;
    sint[gid] = s;
}

// ---------------- bf16 GEMM: C[M,N] = A[M,K] * B[N,K]^T ----------------
// m97 structure: global_load_lds width-16 staging, linear LDS, 2-barrier loop.
// 128 x BN tile, 4 waves (2x2); per-wave 64 x BN/2 = 4 x (BN/32) fragments of 16x16x32.
template<int BN, bool OUT_BF16>
__global__ __launch_bounds__(256) void k_gemm_bt(const ushort_t* __restrict__ A,
                                                 const ushort_t* __restrict__ B,
                                                 void* __restrict__ C,
                                                 int M, int N, int K)
{
    constexpr int NF = BN / 32;
    __shared__ __align__(16) ushort_t As[128 * 32];
    __shared__ __align__(16) ushort_t Bs[BN * 32];
    const int tid = threadIdx.x;
    const int lane = tid & 63;
    const int w = tid >> 6;
    const int wr = w >> 1, wc = w & 1;
    const int l15 = lane & 15, hi = lane >> 4;
    const int m0 = blockIdx.y * 128, n0 = blockIdx.x * BN;
    const int srow = lane >> 2, skc = (lane & 3) * 8;   // staging: 16 rows x 64B per 1KB chunk

    f32x4 acc[4][NF] = {};

    for (int k0 = 0; k0 < K; k0 += 32){
        __syncthreads();
        #pragma unroll
        for (int i = 0; i < 2; ++i){                     // A: 8 chunks, wave does 2
            int c = w * 2 + i;
            gld16(&A[(size_t)(m0 + c * 16 + srow) * K + k0 + skc], &As[c * 512]);
        }
        #pragma unroll
        for (int i = 0; i < BN / 64; ++i){               // B: BN/16 chunks
            int c = w * (BN / 64) + i;
            gld16(&B[(size_t)(n0 + c * 16 + srow) * K + k0 + skc], &Bs[c * 512]);
        }
        __syncthreads();                                  // compiler drains vmcnt here
        bf16x8 af[4], bfr[NF];
        #pragma unroll
        for (int mi = 0; mi < 4; ++mi)
            af[mi] = *(const bf16x8*)&As[(wr * 64 + mi * 16 + l15) * 32 + hi * 8];
        #pragma unroll
        for (int ni = 0; ni < NF; ++ni)
            bfr[ni] = *(const bf16x8*)&Bs[(wc * (BN / 2) + ni * 16 + l15) * 32 + hi * 8];
        #pragma unroll
        for (int mi = 0; mi < 4; ++mi)
            #pragma unroll
            for (int ni = 0; ni < NF; ++ni)
                acc[mi][ni] = __builtin_amdgcn_mfma_f32_16x16x32_bf16(af[mi], bfr[ni], acc[mi][ni], 0, 0, 0);
    }

    #pragma unroll
    for (int mi = 0; mi < 4; ++mi){
        #pragma unroll
        for (int ni = 0; ni < NF; ++ni){
            #pragma unroll
            for (int r = 0; r < 4; ++r){
                int row = m0 + wr * 64 + mi * 16 + hi * 4 + r;
                int col = n0 + wc * (BN / 2) + ni * 16 + l15;
                float v = acc[mi][ni][r];
                if (OUT_BF16) ((ushort_t*)C)[(size_t)row * N + col] = f2bfn(v);
                else          ((float*)C)[(size_t)row * N + col] = v;
            }
        }
    }
}

// ---------------- fuse: RMSNorm + rotary (SCALE*log2e into q), v-mix, V transpose ----------------
__global__ __launch_bounds__(256) void k_fuse(const ushort_t* __restrict__ qkvb,
                                              const float* __restrict__ ve,
                                              const float* __restrict__ lam,
                                              const float* __restrict__ cost,
                                              const float* __restrict__ sint,
                                              ushort_t* __restrict__ qb,
                                              ushort_t* __restrict__ kb,
                                              ushort_t* __restrict__ vtb)
{
    const int h  = blockIdx.y;
    const int t0 = blockIdx.x * 64;
    const int tid = threadIdx.x;
    const int tl = tid >> 2;
    const int dg = tid & 3;
    const int t  = t0 + tl;

    __shared__ __align__(16) float vtile[32 * 65];

    float cs[8], sn[8];
    #pragma unroll
    for (int j = 0; j < 8; ++j){
        int ci = (dg * 8 + j) & 15;
        cs[j] = cost[t * 16 + ci];
        sn[j] = sint[t * 16 + ci];
    }
    const float sgn = (dg < 2) ? 1.0f : -1.0f;

    #pragma unroll
    for (int which = 0; which < 2; ++which){
        u16x8 raw = *(const u16x8*)&qkvb[(size_t)t * 3072 + which * 1024 + h * 32 + dg * 8];
        float v[8];
        float ss = 0.0f;
        #pragma unroll
        for (int j = 0; j < 8; ++j){ v[j] = bf2f(raw[j]); ss += v[j] * v[j]; }
        ss += __shfl_xor(ss, 1);
        ss += __shfl_xor(ss, 2);
        const float inv = rsqrtf(ss * (1.0f / 32.0f) + RMS_EPS_);
        const float scl = (which == 0) ? SCALE_ * LOG2E_ : 1.0f;  // scores end up in log2 domain
        u16x8 o;
        #pragma unroll
        for (int j = 0; j < 8; ++j){
            float nv = v[j] * inv;
            float p  = __shfl_xor(nv, 2);
            o[j] = f2bfn((nv * cs[j] + sgn * p * sn[j]) * scl);
        }
        ushort_t* dst = (which == 0) ? qb : kb;
        *(u16x8*)&dst[((size_t)h * TSEQ + t) * 32 + dg * 8] = o;
    }

    const float l0 = lam[0], l1 = lam[1];
    {
        u16x8 raw = *(const u16x8*)&qkvb[(size_t)t * 3072 + 2048 + h * 32 + dg * 8];
        const float4* vep = (const float4*)&ve[(size_t)t * 1024 + h * 32 + dg * 8];
        float4 a = vep[0], b = vep[1];
        float vef[8] = {a.x, a.y, a.z, a.w, b.x, b.y, b.z, b.w};
        #pragma unroll
        for (int j = 0; j < 8; ++j)
            vtile[(dg * 8 + j) * 65 + tl] = l0 * bf2f(raw[j]) + l1 * vef[j];
    }
    __syncthreads();
    {
        const int d = tid >> 3, jj = tid & 7;
        u16x8 o;
        #pragma unroll
        for (int e = 0; e < 8; ++e)
            o[e] = f2bfn(vtile[d * 65 + jj * 8 + e]);
        *(u16x8*)&vtb[((size_t)h * HD_ + d) * TSEQ + t0 + jj * 8] = o;
    }
}

// ---------------- causal flash attention ----------------
// One key-tile step. Scores arrive pre-scaled by SCALE*log2e -> exp2 softmax.
template<bool MASK>
__device__ __forceinline__ void attn_tile(const ushort_t* __restrict__ kb,
                                          const ushort_t* __restrict__ vtb,
                                          ushort_t* pb, const bf16x8& q_frag,
                                          int h, int kb0, int qw, int l15, int hi,
                                          f32x4& acc0, f32x4& acc1, float* m, float* lp)
{
    // V loads issued early: HBM/L2 latency hides under QK^T + softmax
    bf16x8 vv0[2], vv1[2];
    #pragma unroll
    for (int kk = 0; kk < 2; ++kk){
        vv0[kk] = *(const bf16x8*)&vtb[((size_t)h * HD_ + l15) * TSEQ + kb0 + kk * 32 + hi * 8];
        vv1[kk] = *(const bf16x8*)&vtb[((size_t)h * HD_ + 16 + l15) * TSEQ + kb0 + kk * 32 + hi * 8];
    }
    f32x4 s[4];
    #pragma unroll
    for (int ni = 0; ni < 4; ++ni){
        bf16x8 kf = *(const bf16x8*)&kb[((size_t)h * TSEQ + kb0 + ni * 16 + l15) * 32 + hi * 8];
        f32x4 z = {0.f, 0.f, 0.f, 0.f};
        s[ni] = __builtin_amdgcn_mfma_f32_16x16x32_bf16(q_frag, kf, z, 0, 0, 0);
    }
    if (MASK){
        #pragma unroll
        for (int ni = 0; ni < 4; ++ni){
            int col = kb0 + ni * 16 + l15;
            #pragma unroll
            for (int r = 0; r < 4; ++r)
                if (col > qw + hi * 4 + r) s[ni][r] = -1e30f;
        }
    }
    float sc[4];
    #pragma unroll
    for (int r = 0; r < 4; ++r){
        float mt = fmaxf(fmaxf(s[0][r], s[1][r]), fmaxf(s[2][r], s[3][r]));
        mt = fmaxf(mt, __shfl_xor(mt, 1));
        mt = fmaxf(mt, __shfl_xor(mt, 2));
        mt = fmaxf(mt, __shfl_xor(mt, 4));
        mt = fmaxf(mt, __shfl_xor(mt, 8));
        float mn = fmaxf(m[r], mt);
        sc[r] = fexp2(m[r] - mn);
        m[r] = mn;
    }
    #pragma unroll
    for (int r = 0; r < 4; ++r){
        float ps = 0.f;
        #pragma unroll
        for (int ni = 0; ni < 4; ++ni){
            float p = fexp2(s[ni][r] - m[r]);
            s[ni][r] = p;
            ps += p;
        }
        lp[r] = lp[r] * sc[r] + ps;   // per-lane partial rowsum; sc is row-uniform
        acc0[r] *= sc[r];
        acc1[r] *= sc[r];
    }
    #pragma unroll
    for (int ni = 0; ni < 4; ++ni)
        #pragma unroll
        for (int r = 0; r < 4; ++r)
            pb[(hi * 4 + r) * 72 + ni * 16 + l15] = f2bfn(s[ni][r]);
    #pragma unroll
    for (int kk = 0; kk < 2; ++kk){
        bf16x8 pf = *(const bf16x8*)&pb[l15 * 72 + kk * 32 + hi * 8];
        acc0 = __builtin_amdgcn_mfma_f32_16x16x32_bf16(pf, vv0[kk], acc0, 0, 0, 0);
        acc1 = __builtin_amdgcn_mfma_f32_16x16x32_bf16(pf, vv1[kk], acc1, 0, 0, 0);
    }
}

// grid (16, NHEADS): block b handles complementary q-tiles {b, 31-b} -> 33 key-tiles each (balanced).
__global__ __launch_bounds__(256) void k_attn(const ushort_t* __restrict__ qb,
                                              const ushort_t* __restrict__ kb,
                                              const ushort_t* __restrict__ vtb,
                                              ushort_t* __restrict__ yb)
{
    const int h  = blockIdx.y;
    const int tid = threadIdx.x;
    const int w = tid >> 6, lane = tid & 63;
    const int l15 = lane & 15, hi = lane >> 4;

    __shared__ __align__(16) ushort_t Pbuf[4][16 * 72];
    ushort_t* pb = &Pbuf[w][0];

    for (int half = 0; half < 2; ++half){
        const int qt = half ? (31 - (int)blockIdx.x) : (int)blockIdx.x;
        const int qw = qt * 64 + w * 16;
        const bf16x8 q_frag = *(const bf16x8*)&qb[((size_t)h * TSEQ + qw + l15) * 32 + hi * 8];

        f32x4 acc0 = {0.f, 0.f, 0.f, 0.f}, acc1 = {0.f, 0.f, 0.f, 0.f};
        float m[4]  = {-1e30f, -1e30f, -1e30f, -1e30f};
        float lp[4] = {0.f, 0.f, 0.f, 0.f};

        for (int kt = 0; kt < qt; ++kt)
            attn_tile<false>(kb, vtb, pb, q_frag, h, kt * 64, qw, l15, hi, acc0, acc1, m, lp);
        attn_tile<true>(kb, vtb, pb, q_frag, h, qt * 64, qw, l15, hi, acc0, acc1, m, lp);

        #pragma unroll
        for (int r = 0; r < 4; ++r){
            float ls = lp[r];
            ls += __shfl_xor(ls, 1);
            ls += __shfl_xor(ls, 2);
            ls += __shfl_xor(ls, 4);
            ls += __shfl_xor(ls, 8);
            float inv = 1.0f / ls;
            int row = qw + hi * 4 + r;
            yb[(size_t)row * 1024 + h * 32 + l15]      = f2bfn(acc0[r] * inv);
            yb[(size_t)row * 1024 + h * 32 + 16 + l15] = f2bfn(acc1[r] * inv);
        }
    }
}

// ---------------- launcher ----------------
extern "C" void kernel_launch(void* const* d_in, const int* in_sizes, int n_in,
                              void* d_out, int out_size, void* d_ws, size_t ws_size,
                              hipStream_t stream)
{
    const float* x   = (const float*)d_in[0];
    const float* ve  = (const float*)d_in[1];
    const float* qkw = (const float*)d_in[2];
    const float* lam = (const float*)d_in[3];
    const float* cpw = (const float*)d_in[4];

    char* ws = (char*)d_ws;
    size_t o = 0;
    auto take = [&](size_t bytes) -> char* {
        char* p = ws + o; o += (bytes + 255) & ~(size_t)255; return p;
    };
    ushort_t* xb   = (ushort_t*)take((size_t)TSEQ * 1024 * 2);
    ushort_t* wb   = (ushort_t*)take((size_t)3072 * 1024 * 2);
    ushort_t* cpb  = (ushort_t*)take((size_t)1024 * 1024 * 2);
    ushort_t* qkvb = (ushort_t*)take((size_t)TSEQ * 3072 * 2);
    float*    cost = (float*)take((size_t)TSEQ * 16 * 4);
    float*    sint = (float*)take((size_t)TSEQ * 16 * 4);
    ushort_t* qb   = (ushort_t*)take((size_t)NHEADS * TSEQ * HD_ * 2);
    ushort_t* kb   = (ushort_t*)take((size_t)NHEADS * TSEQ * HD_ * 2);
    ushort_t* vtb  = (ushort_t*)take((size_t)NHEADS * HD_ * TSEQ * 2);
    ushort_t* yb   = xb;  // xb dead after QKV GEMM; reuse for y

    k_convert<<<512, 256, 0, stream>>>(x,   xb,  TSEQ * 1024 / 4);
    k_convert<<<768, 256, 0, stream>>>(qkw, wb,  3072 * 1024 / 4);
    k_convert<<<256, 256, 0, stream>>>(cpw, cpb, 1024 * 1024 / 4);
    k_tables<<<TSEQ * 16 / 256, 256, 0, stream>>>(cost, sint);
    k_gemm_bt<128, true ><<<dim3(3072 / 128, TSEQ / 128), 256, 0, stream>>>(xb, wb, qkvb, TSEQ, 3072, 1024);
    k_fuse<<<dim3(TSEQ / 64, NHEADS), 256, 0, stream>>>(qkvb, ve, lam, cost, sint, qb, kb, vtb);
    k_attn<<<dim3(16, NHEADS), 256, 0, stream>>>(qb, kb, vtb, yb);
    k_gemm_bt<64, false><<<dim3(1024 / 64, TSEQ / 128), 256, 0, stream>>>(yb, cpb, (float*)d_out, TSEQ, 1024, 1024);
}

// Round 3
// 181.960 us; speedup vs baseline: 1.3008x; 1.0440x over previous
//
#include <hip/hip_runtime.h>
#include <hip/hip_bf16.h>

#define NHEADS 32
#define HD_ 32
#define TSEQ 2048
#define SCALE_ 0.12f
#define LOG2E_ 1.44269504088896f
#define RMS_EPS_ 1.1920929e-07f

typedef unsigned short ushort_t;
typedef __bf16 bf16_t;
typedef __attribute__((ext_vector_type(8))) bf16_t bf16x8;
typedef __attribute__((ext_vector_type(4))) float f32x4;
typedef __attribute__((ext_vector_type(8))) unsigned short u16x8;

__device__ __forceinline__ ushort_t f2bfn(float f){
    __hip_bfloat16 b = __float2bfloat16(f);
    return *reinterpret_cast<ushort_t*>(&b);
}
__device__ __forceinline__ float bf2f(ushort_t s){
    union { unsigned u; float f; } v; v.u = ((unsigned)s) << 16;
    return v.f;
}
__device__ __forceinline__ float fexp2(float x){
#if __has_builtin(__builtin_amdgcn_exp2f)
    return __builtin_amdgcn_exp2f(x);
#else
    return exp2f(x);
#endif
}
__device__ __forceinline__ void gld16(const void* g, void* l){
    __builtin_amdgcn_global_load_lds(
        (const __attribute__((address_space(1))) unsigned int*)g,
        (__attribute__((address_space(3))) unsigned int*)l,
        16, 0, 0);
}

// ---------------- fp32 -> bf16 convert ----------------
__global__ __launch_bounds__(256) void k_convert(const float* __restrict__ src,
                                                 ushort_t* __restrict__ dst, int n4){
    int i = blockIdx.x * blockDim.x + threadIdx.x;
    int stride = gridDim.x * blockDim.x;
    for (; i < n4; i += stride){
        float4 v = ((const float4*)src)[i];
        ushort4 o;
        o.x = f2bfn(v.x); o.y = f2bfn(v.y); o.z = f2bfn(v.z); o.w = f2bfn(v.w);
        ((ushort4*)dst)[i] = o;
    }
}

// ---------------- rotary tables ----------------
__global__ __launch_bounds__(256) void k_tables(float* __restrict__ cost, float* __restrict__ sint){
    int gid = blockIdx.x * 256 + threadIdx.x;
    if (gid >= TSEQ * 16) return;
    int t = gid >> 4, i = gid & 15;
    float c = 1.0f, s = 0.0f;
    if (i < 8){
        float af = powf(1.0f / 128.0f, (float)i * (1.0f / 7.0f));
        float th = (float)t * af;
        sincosf(th, &s, &c);
    }
    cost[gid] = c;
    sint[gid] = s;
}

// ---------------- bf16 GEMM, BK=64: C[M,N] = A[M,K]*B[N,K]^T ----------------
// 4 waves (2x2). Per-wave (BM/2)x(BN/2). global_load_lds staging, linear LDS.
template<int BM, int BN, bool OUT_BF16>
__global__ __launch_bounds__(256) void k_gemm64(const ushort_t* __restrict__ A,
                                                const ushort_t* __restrict__ B,
                                                void* __restrict__ C,
                                                int M, int N, int K)
{
    constexpr int MI = BM / 32, NI = BN / 32;
    __shared__ __align__(16) ushort_t As[BM * 64];
    __shared__ __align__(16) ushort_t Bs[BN * 64];
    const int tid = threadIdx.x;
    const int lane = tid & 63;
    const int w = tid >> 6;
    const int wr = w >> 1, wc = w & 1;
    const int l15 = lane & 15, hi = lane >> 4;
    const int m0 = blockIdx.y * BM, n0 = blockIdx.x * BN;
    const int srow = lane >> 3, scol = (lane & 7) * 8;   // 8 rows x 128B per 1KB chunk

    f32x4 acc[MI][NI] = {};

    for (int k0 = 0; k0 < K; k0 += 64){
        __syncthreads();
        #pragma unroll
        for (int i = 0; i < BM / 32; ++i){
            int c = w * (BM / 32) + i;
            gld16(&A[(size_t)(m0 + c * 8 + srow) * K + k0 + scol], &As[c * 512]);
        }
        #pragma unroll
        for (int i = 0; i < BN / 32; ++i){
            int c = w * (BN / 32) + i;
            gld16(&B[(size_t)(n0 + c * 8 + srow) * K + k0 + scol], &Bs[c * 512]);
        }
        __syncthreads();
        bf16x8 af[MI][2], bfr[NI][2];
        #pragma unroll
        for (int mi = 0; mi < MI; ++mi)
            #pragma unroll
            for (int sub = 0; sub < 2; ++sub)
                af[mi][sub] = *(const bf16x8*)&As[(wr * (BM/2) + mi * 16 + l15) * 64 + sub * 32 + hi * 8];
        #pragma unroll
        for (int ni = 0; ni < NI; ++ni)
            #pragma unroll
            for (int sub = 0; sub < 2; ++sub)
                bfr[ni][sub] = *(const bf16x8*)&Bs[(wc * (BN/2) + ni * 16 + l15) * 64 + sub * 32 + hi * 8];
        #pragma unroll
        for (int sub = 0; sub < 2; ++sub)
            #pragma unroll
            for (int mi = 0; mi < MI; ++mi)
                #pragma unroll
                for (int ni = 0; ni < NI; ++ni)
                    acc[mi][ni] = __builtin_amdgcn_mfma_f32_16x16x32_bf16(af[mi][sub], bfr[ni][sub], acc[mi][ni], 0, 0, 0);
    }

    #pragma unroll
    for (int mi = 0; mi < MI; ++mi)
        #pragma unroll
        for (int ni = 0; ni < NI; ++ni)
            #pragma unroll
            for (int r = 0; r < 4; ++r){
                int row = m0 + wr * (BM/2) + mi * 16 + hi * 4 + r;
                int col = n0 + wc * (BN/2) + ni * 16 + l15;
                float v = acc[mi][ni][r];
                if (OUT_BF16) ((ushort_t*)C)[(size_t)row * N + col] = f2bfn(v);
                else          ((float*)C)[(size_t)row * N + col] = v;
            }
}

// ---------------- fuse: RMSNorm + rotary (SCALE*log2e into q), v-mix, V transpose ----------------
__global__ __launch_bounds__(256) void k_fuse(const ushort_t* __restrict__ qkvb,
                                              const float* __restrict__ ve,
                                              const float* __restrict__ lam,
                                              const float* __restrict__ cost,
                                              const float* __restrict__ sint,
                                              ushort_t* __restrict__ qb,
                                              ushort_t* __restrict__ kb,
                                              ushort_t* __restrict__ vtb)
{
    const int h  = blockIdx.y;
    const int t0 = blockIdx.x * 64;
    const int tid = threadIdx.x;
    const int tl = tid >> 2;
    const int dg = tid & 3;
    const int t  = t0 + tl;

    __shared__ __align__(16) float vtile[32 * 65];

    float cs[8], sn[8];
    #pragma unroll
    for (int j = 0; j < 8; ++j){
        int ci = (dg * 8 + j) & 15;
        cs[j] = cost[t * 16 + ci];
        sn[j] = sint[t * 16 + ci];
    }
    const float sgn = (dg < 2) ? 1.0f : -1.0f;

    #pragma unroll
    for (int which = 0; which < 2; ++which){
        u16x8 raw = *(const u16x8*)&qkvb[(size_t)t * 3072 + which * 1024 + h * 32 + dg * 8];
        float v[8];
        float ss = 0.0f;
        #pragma unroll
        for (int j = 0; j < 8; ++j){ v[j] = bf2f(raw[j]); ss += v[j] * v[j]; }
        ss += __shfl_xor(ss, 1);
        ss += __shfl_xor(ss, 2);
        const float inv = rsqrtf(ss * (1.0f / 32.0f) + RMS_EPS_);
        const float scl = (which == 0) ? SCALE_ * LOG2E_ : 1.0f;
        u16x8 o;
        #pragma unroll
        for (int j = 0; j < 8; ++j){
            float nv = v[j] * inv;
            float p  = __shfl_xor(nv, 2);
            o[j] = f2bfn((nv * cs[j] + sgn * p * sn[j]) * scl);
        }
        ushort_t* dst = (which == 0) ? qb : kb;
        *(u16x8*)&dst[((size_t)h * TSEQ + t) * 32 + dg * 8] = o;
    }

    const float l0 = lam[0], l1 = lam[1];
    {
        u16x8 raw = *(const u16x8*)&qkvb[(size_t)t * 3072 + 2048 + h * 32 + dg * 8];
        const float4* vep = (const float4*)&ve[(size_t)t * 1024 + h * 32 + dg * 8];
        float4 a = vep[0], b = vep[1];
        float vef[8] = {a.x, a.y, a.z, a.w, b.x, b.y, b.z, b.w};
        #pragma unroll
        for (int j = 0; j < 8; ++j)
            vtile[(dg * 8 + j) * 65 + tl] = l0 * bf2f(raw[j]) + l1 * vef[j];
    }
    __syncthreads();
    {
        const int d = tid >> 3, jj = tid & 7;
        u16x8 o;
        #pragma unroll
        for (int e = 0; e < 8; ++e)
            o[e] = f2bfn(vtile[d * 65 + jj * 8 + e]);
        *(u16x8*)&vtb[((size_t)h * HD_ + d) * TSEQ + t0 + jj * 8] = o;
    }
}

// ---------------- causal flash attention (swapped QK^T, intra-block key-split) ----------------
struct ChainState { f32x4 a0, a1; float m, lp; };

// One 64-key tile. Swapped: s = mfma(K,Q) -> D[key][q], col(l15)=q, row(4hi+r)=key.
template<bool MASK>
__device__ __forceinline__ void attn_tile(const ushort_t* __restrict__ kb_h,
                                          const ushort_t* __restrict__ vt_h,
                                          ushort_t* pb, const bf16x8& qf,
                                          int kb0, int qglob, int l15, int hi,
                                          ChainState& st)
{
    bf16x8 vv0[2], vv1[2];
    #pragma unroll
    for (int kk = 0; kk < 2; ++kk){
        vv0[kk] = *(const bf16x8*)&vt_h[(size_t)l15 * TSEQ + kb0 + kk * 32 + hi * 8];
        vv1[kk] = *(const bf16x8*)&vt_h[(size_t)(16 + l15) * TSEQ + kb0 + kk * 32 + hi * 8];
    }
    f32x4 s[4];
    #pragma unroll
    for (int ni = 0; ni < 4; ++ni){
        bf16x8 kf = *(const bf16x8*)&kb_h[(size_t)(kb0 + ni * 16 + l15) * 32 + hi * 8];
        f32x4 z = {0.f, 0.f, 0.f, 0.f};
        s[ni] = __builtin_amdgcn_mfma_f32_16x16x32_bf16(kf, qf, z, 0, 0, 0);  // S^T
    }
    if (MASK){
        #pragma unroll
        for (int ni = 0; ni < 4; ++ni)
            #pragma unroll
            for (int r = 0; r < 4; ++r)
                if (kb0 + ni * 16 + hi * 4 + r > qglob) s[ni][r] = -1e30f;
    }
    // per-lane max over 16 values (one q-row), then cross-hi (2 shuffles)
    float mt = -1e30f;
    #pragma unroll
    for (int ni = 0; ni < 4; ++ni)
        #pragma unroll
        for (int r = 0; r < 4; ++r)
            mt = fmaxf(mt, s[ni][r]);
    mt = fmaxf(mt, __shfl_xor(mt, 16));
    mt = fmaxf(mt, __shfl_xor(mt, 32));
    float mn = fmaxf(st.m, mt);
    float sc = fexp2(st.m - mn);
    st.m = mn;
    float ps = 0.f;
    #pragma unroll
    for (int ni = 0; ni < 4; ++ni)
        #pragma unroll
        for (int r = 0; r < 4; ++r){
            float p = fexp2(s[ni][r] - mn);
            s[ni][r] = p;
            ps += p;
        }
    st.lp = st.lp * sc + ps;          // per-lane partial (reduced at the end)
    #pragma unroll
    for (int r = 0; r < 4; ++r){ st.a0[r] *= sc; st.a1[r] *= sc; }
    // P^T[q][key] -> LDS: 4x ds_write_b64 (keys 16ni+4hi..+3 of row l15)
    #pragma unroll
    for (int ni = 0; ni < 4; ++ni){
        ushort4 pk;
        pk.x = f2bfn(s[ni][0]); pk.y = f2bfn(s[ni][1]);
        pk.z = f2bfn(s[ni][2]); pk.w = f2bfn(s[ni][3]);
        *(ushort4*)&pb[l15 * 72 + ni * 16 + hi * 4] = pk;
    }
    // PV: O^T = V^T * P^T. A=V^T (row=l15=d), B=P^T (col=l15=q). acc col=q, row=d.
    #pragma unroll
    for (int kk = 0; kk < 2; ++kk){
        bf16x8 pf = *(const bf16x8*)&pb[l15 * 72 + kk * 32 + hi * 8];
        st.a0 = __builtin_amdgcn_mfma_f32_16x16x32_bf16(vv0[kk], pf, st.a0, 0, 0, 0);
        st.a1 = __builtin_amdgcn_mfma_f32_16x16x32_bf16(vv1[kk], pf, st.a1, 0, 0, 0);
    }
}

__device__ __forceinline__ void run_range(const ushort_t* kb_h, const ushort_t* vt_h,
                                          ushort_t* pb, const bf16x8& qf, int qglob,
                                          int lo, int hi_t, int nT, int l15, int hi,
                                          ChainState& st)
{
    int stop = (hi_t < nT) ? hi_t : (nT - 1);
    for (int kt = lo; kt < stop; ++kt)
        attn_tile<false>(kb_h, vt_h, pb, qf, kt * 64, qglob, l15, hi, st);
    if (hi_t == nT && lo < nT)
        attn_tile<true>(kb_h, vt_h, pb, qf, (nT - 1) * 64, qglob, l15, hi, st);
}

__device__ __forceinline__ void merge_state(ChainState& s, const float* mb){
    float m2 = mb[0];
    float mn = fmaxf(s.m, m2);
    float f1 = fexp2(s.m - mn), f2 = fexp2(m2 - mn);
    s.lp = s.lp * f1 + mb[1] * f2;
    #pragma unroll
    for (int r = 0; r < 4; ++r){
        s.a0[r] = s.a0[r] * f1 + mb[2 + r] * f2;
        s.a1[r] = s.a1[r] * f1 + mb[6 + r] * f2;
    }
    s.m = mn;
}

// grid (16, NHEADS), block 512 = 8 waves.
// Block b: q-tiles {b, 31-b}. Strip ws=w&3 (16 rows); chunk half2=w>>2 splits key range.
__global__ __launch_bounds__(512, 4) void k_attn(const ushort_t* __restrict__ qb,
                                                 const ushort_t* __restrict__ kb,
                                                 const ushort_t* __restrict__ vtb,
                                                 ushort_t* __restrict__ yb)
{
    const int h  = blockIdx.y;
    const int b  = blockIdx.x;
    const int tid = threadIdx.x;
    const int w = tid >> 6, lane = tid & 63;
    const int ws = w & 3, half2 = w >> 2;
    const int l15 = lane & 15, hi = lane >> 4;

    __shared__ __align__(16) ushort_t Pall[8][16 * 72];
    __shared__ float mbuf[4][64][20];
    ushort_t* pb = &Pall[w][0];

    const ushort_t* kb_h = kb + (size_t)h * TSEQ * HD_;
    const ushort_t* vt_h = vtb + (size_t)h * HD_ * TSEQ;
    const ushort_t* qb_h = qb + (size_t)h * TSEQ * HD_;

    const int qtA = b, qtB = 31 - b;
    const int nA = qtA + 1, nB = qtB + 1;
    const int hA = (nA + 1) >> 1, hB = nB >> 1;

    const int qwA = qtA * 64 + ws * 16;
    const int qwB = qtB * 64 + ws * 16;
    const bf16x8 qfA = *(const bf16x8*)&qb_h[(size_t)(qwA + l15) * 32 + hi * 8];
    const bf16x8 qfB = *(const bf16x8*)&qb_h[(size_t)(qwB + l15) * 32 + hi * 8];

    ChainState stA, stB;
    stA.a0 = {0.f,0.f,0.f,0.f}; stA.a1 = {0.f,0.f,0.f,0.f}; stA.m = -1e30f; stA.lp = 0.f;
    stB = stA;

    if (half2 == 0){
        run_range(kb_h, vt_h, pb, qfA, qwA + l15, 0, hA, nA, l15, hi, stA);
        run_range(kb_h, vt_h, pb, qfB, qwB + l15, 0, hB, nB, l15, hi, stB);
    } else {
        run_range(kb_h, vt_h, pb, qfA, qwA + l15, hA, nA, nA, l15, hi, stA);
        run_range(kb_h, vt_h, pb, qfB, qwB + l15, hB, nB, nB, l15, hi, stB);
    }

    if (half2 == 1){
        float* mb = &mbuf[ws][lane][0];
        mb[0] = stA.m; mb[1] = stA.lp;
        #pragma unroll
        for (int r = 0; r < 4; ++r){ mb[2 + r] = stA.a0[r]; mb[6 + r] = stA.a1[r]; }
        mb[10] = stB.m; mb[11] = stB.lp;
        #pragma unroll
        for (int r = 0; r < 4; ++r){ mb[12 + r] = stB.a0[r]; mb[16 + r] = stB.a1[r]; }
    }
    __syncthreads();
    if (half2 == 0){
        merge_state(stA, &mbuf[ws][lane][0]);
        merge_state(stB, &mbuf[ws][lane][10]);
        #pragma unroll
        for (int which = 0; which < 2; ++which){
            ChainState& st = which ? stB : stA;
            int qw = which ? qwB : qwA;
            float ls = st.lp;
            ls += __shfl_xor(ls, 16);
            ls += __shfl_xor(ls, 32);
            float inv = 1.0f / ls;
            ushort4 o0, o1;
            o0.x = f2bfn(st.a0[0]*inv); o0.y = f2bfn(st.a0[1]*inv);
            o0.z = f2bfn(st.a0[2]*inv); o0.w = f2bfn(st.a0[3]*inv);
            o1.x = f2bfn(st.a1[0]*inv); o1.y = f2bfn(st.a1[1]*inv);
            o1.z = f2bfn(st.a1[2]*inv); o1.w = f2bfn(st.a1[3]*inv);
            size_t base = (size_t)(qw + l15) * 1024 + h * 32;
            *(ushort4*)&yb[base + hi * 4]      = o0;
            *(ushort4*)&yb[base + 16 + hi * 4] = o1;
        }
    }
}

// ---------------- launcher ----------------
extern "C" void kernel_launch(void* const* d_in, const int* in_sizes, int n_in,
                              void* d_out, int out_size, void* d_ws, size_t ws_size,
                              hipStream_t stream)
{
    const float* x   = (const float*)d_in[0];
    const float* ve  = (const float*)d_in[1];
    const float* qkw = (const float*)d_in[2];
    const float* lam = (const float*)d_in[3];
    const float* cpw = (const float*)d_in[4];

    char* ws = (char*)d_ws;
    size_t o = 0;
    auto take = [&](size_t bytes) -> char* {
        char* p = ws + o; o += (bytes + 255) & ~(size_t)255; return p;
    };
    ushort_t* xb   = (ushort_t*)take((size_t)TSEQ * 1024 * 2);
    ushort_t* wb   = (ushort_t*)take((size_t)3072 * 1024 * 2);
    ushort_t* cpb  = (ushort_t*)take((size_t)1024 * 1024 * 2);
    ushort_t* qkvb = (ushort_t*)take((size_t)TSEQ * 3072 * 2);
    float*    cost = (float*)take((size_t)TSEQ * 16 * 4);
    float*    sint = (float*)take((size_t)TSEQ * 16 * 4);
    ushort_t* qb   = (ushort_t*)take((size_t)NHEADS * TSEQ * HD_ * 2);
    ushort_t* kb   = (ushort_t*)take((size_t)NHEADS * TSEQ * HD_ * 2);
    ushort_t* vtb  = (ushort_t*)take((size_t)NHEADS * HD_ * TSEQ * 2);
    ushort_t* yb   = xb;  // xb dead after QKV GEMM; reuse for y

    k_convert<<<512, 256, 0, stream>>>(x,   xb,  TSEQ * 1024 / 4);
    k_convert<<<768, 256, 0, stream>>>(qkw, wb,  3072 * 1024 / 4);
    k_convert<<<256, 256, 0, stream>>>(cpw, cpb, 1024 * 1024 / 4);
    k_tables<<<TSEQ * 16 / 256, 256, 0, stream>>>(cost, sint);
    k_gemm64<64, 128, true ><<<dim3(3072 / 128, TSEQ / 64), 256, 0, stream>>>(xb, wb, qkvb, TSEQ, 3072, 1024);
    k_fuse<<<dim3(TSEQ / 64, NHEADS), 256, 0, stream>>>(qkvb, ve, lam, cost, sint, qb, kb, vtb);
    k_attn<<<dim3(16, NHEADS), 512, 0, stream>>>(qb, kb, vtb, yb);
    k_gemm64<64, 64, false><<<dim3(1024 / 64, TSEQ / 64), 256, 0, stream>>>(yb, cpb, (float*)d_out, TSEQ, 1024, 1024);
}

// Round 4
// 161.479 us; speedup vs baseline: 1.4657x; 1.1268x over previous
//
#include <hip/hip_runtime.h>
#include <hip/hip_bf16.h>

#define NHEADS 32
#define HD_ 32
#define TSEQ 2048
#define SCALE_ 0.12f
#define LOG2E_ 1.44269504088896f
#define RMS_EPS_ 1.1920929e-07f

typedef unsigned short ushort_t;
typedef __bf16 bf16_t;
typedef __attribute__((ext_vector_type(8))) bf16_t bf16x8;
typedef __attribute__((ext_vector_type(4))) float f32x4;
typedef __attribute__((ext_vector_type(8))) unsigned short u16x8;

__device__ __forceinline__ ushort_t f2bfn(float f){
    __hip_bfloat16 b = __float2bfloat16(f);
    return *reinterpret_cast<ushort_t*>(&b);
}
__device__ __forceinline__ float bf2f(ushort_t s){
    union { unsigned u; float f; } v; v.u = ((unsigned)s) << 16;
    return v.f;
}
__device__ __forceinline__ float fexp2(float x){
#if __has_builtin(__builtin_amdgcn_exp2f)
    return __builtin_amdgcn_exp2f(x);
#else
    return exp2f(x);
#endif
}
__device__ __forceinline__ void gld16(const void* g, void* l){
    __builtin_amdgcn_global_load_lds(
        (const __attribute__((address_space(1))) unsigned int*)g,
        (__attribute__((address_space(3))) unsigned int*)l,
        16, 0, 0);
}

// ---------------- prep: fp32->bf16 converts + rotary tables, one launch ----------------
__global__ __launch_bounds__(256) void k_prep(const float* __restrict__ x,
                                              const float* __restrict__ qkw,
                                              const float* __restrict__ cpw,
                                              ushort_t* __restrict__ xb,
                                              ushort_t* __restrict__ wb,
                                              ushort_t* __restrict__ cpb,
                                              float* __restrict__ cost,
                                              float* __restrict__ sint)
{
    const int n1 = TSEQ * 1024 / 4, n2 = 3 * 1024 * 1024 / 4, n3 = 1024 * 1024 / 4;
    int i = blockIdx.x * 256 + threadIdx.x;
    if (i < n1 + n2 + n3){
        const float* src; ushort_t* dst; int j = i;
        if (j < n1){ src = x; dst = xb; }
        else if (j < n1 + n2){ j -= n1; src = qkw; dst = wb; }
        else { j -= n1 + n2; src = cpw; dst = cpb; }
        float4 v = ((const float4*)src)[j];
        ushort4 o;
        o.x = f2bfn(v.x); o.y = f2bfn(v.y); o.z = f2bfn(v.z); o.w = f2bfn(v.w);
        ((ushort4*)dst)[j] = o;
    } else {
        int g = i - (n1 + n2 + n3);
        if (g < TSEQ * 16){
            int t = g >> 4, ii = g & 15;
            float c = 1.0f, s = 0.0f;
            if (ii < 8){
                float af = powf(1.0f / 128.0f, (float)ii * (1.0f / 7.0f));
                sincosf((float)t * af, &s, &c);
            }
            cost[g] = c; sint[g] = s;
        }
    }
}

// ---------------- bf16 GEMM, BK=64, 2-phase double-buffer ----------------
template<int BM, int BN, bool OUT_BF16>
__global__ __launch_bounds__(256) void k_gemm64(const ushort_t* __restrict__ A,
                                                const ushort_t* __restrict__ B,
                                                void* __restrict__ C,
                                                int M, int N, int K)
{
    constexpr int MI = BM / 32, NI = BN / 32;
    __shared__ __align__(16) ushort_t As[2][BM * 64];
    __shared__ __align__(16) ushort_t Bs[2][BN * 64];
    const int tid = threadIdx.x;
    const int lane = tid & 63;
    const int w = tid >> 6;
    const int wr = w >> 1, wc = w & 1;
    const int l15 = lane & 15, hi = lane >> 4;
    const int m0 = blockIdx.y * BM, n0 = blockIdx.x * BN;
    const int srow = lane >> 3, scol = (lane & 7) * 8;

    f32x4 acc[MI][NI] = {};

    auto stage = [&](int k0, int buf){
        #pragma unroll
        for (int i = 0; i < BM / 32; ++i){
            int c = w * (BM / 32) + i;
            gld16(&A[(size_t)(m0 + c * 8 + srow) * K + k0 + scol], &As[buf][c * 512]);
        }
        #pragma unroll
        for (int i = 0; i < BN / 32; ++i){
            int c = w * (BN / 32) + i;
            gld16(&B[(size_t)(n0 + c * 8 + srow) * K + k0 + scol], &Bs[buf][c * 512]);
        }
    };

    stage(0, 0);
    int cur = 0;
    for (int k0 = 0; k0 < K; k0 += 64){
        __syncthreads();                      // compiler drains vmcnt+lgkm here
        if (k0 + 64 < K) stage(k0 + 64, cur ^ 1);   // prefetch overlaps compute below
        bf16x8 af[MI][2], bfr[NI][2];
        #pragma unroll
        for (int mi = 0; mi < MI; ++mi)
            #pragma unroll
            for (int sub = 0; sub < 2; ++sub)
                af[mi][sub] = *(const bf16x8*)&As[cur][(wr * (BM/2) + mi * 16 + l15) * 64 + sub * 32 + hi * 8];
        #pragma unroll
        for (int ni = 0; ni < NI; ++ni)
            #pragma unroll
            for (int sub = 0; sub < 2; ++sub)
                bfr[ni][sub] = *(const bf16x8*)&Bs[cur][(wc * (BN/2) + ni * 16 + l15) * 64 + sub * 32 + hi * 8];
        #pragma unroll
        for (int sub = 0; sub < 2; ++sub)
            #pragma unroll
            for (int mi = 0; mi < MI; ++mi)
                #pragma unroll
                for (int ni = 0; ni < NI; ++ni)
                    acc[mi][ni] = __builtin_amdgcn_mfma_f32_16x16x32_bf16(af[mi][sub], bfr[ni][sub], acc[mi][ni], 0, 0, 0);
        cur ^= 1;
    }

    #pragma unroll
    for (int mi = 0; mi < MI; ++mi)
        #pragma unroll
        for (int ni = 0; ni < NI; ++ni)
            #pragma unroll
            for (int r = 0; r < 4; ++r){
                int row = m0 + wr * (BM/2) + mi * 16 + hi * 4 + r;
                int col = n0 + wc * (BN/2) + ni * 16 + l15;
                float v = acc[mi][ni][r];
                if (OUT_BF16) ((ushort_t*)C)[(size_t)row * N + col] = f2bfn(v);
                else          ((float*)C)[(size_t)row * N + col] = v;
            }
}

// ---------------- fuse: RMSNorm + rotary (SCALE*log2e into q), v-mix, V transpose ----------------
__global__ __launch_bounds__(256) void k_fuse(const ushort_t* __restrict__ qkvb,
                                              const float* __restrict__ ve,
                                              const float* __restrict__ lam,
                                              const float* __restrict__ cost,
                                              const float* __restrict__ sint,
                                              ushort_t* __restrict__ qb,
                                              ushort_t* __restrict__ kb,
                                              ushort_t* __restrict__ vtb)
{
    const int h  = blockIdx.y;
    const int t0 = blockIdx.x * 64;
    const int tid = threadIdx.x;
    const int tl = tid >> 2;
    const int dg = tid & 3;
    const int t  = t0 + tl;

    __shared__ __align__(16) float vtile[32 * 65];

    float cs[8], sn[8];
    #pragma unroll
    for (int j = 0; j < 8; ++j){
        int ci = (dg * 8 + j) & 15;
        cs[j] = cost[t * 16 + ci];
        sn[j] = sint[t * 16 + ci];
    }
    const float sgn = (dg < 2) ? 1.0f : -1.0f;

    #pragma unroll
    for (int which = 0; which < 2; ++which){
        u16x8 raw = *(const u16x8*)&qkvb[(size_t)t * 3072 + which * 1024 + h * 32 + dg * 8];
        float v[8];
        float ss = 0.0f;
        #pragma unroll
        for (int j = 0; j < 8; ++j){ v[j] = bf2f(raw[j]); ss += v[j] * v[j]; }
        ss += __shfl_xor(ss, 1);
        ss += __shfl_xor(ss, 2);
        const float inv = rsqrtf(ss * (1.0f / 32.0f) + RMS_EPS_);
        const float scl = (which == 0) ? SCALE_ * LOG2E_ : 1.0f;
        u16x8 o;
        #pragma unroll
        for (int j = 0; j < 8; ++j){
            float nv = v[j] * inv;
            float p  = __shfl_xor(nv, 2);
            o[j] = f2bfn((nv * cs[j] + sgn * p * sn[j]) * scl);
        }
        ushort_t* dst = (which == 0) ? qb : kb;
        *(u16x8*)&dst[((size_t)h * TSEQ + t) * 32 + dg * 8] = o;
    }

    const float l0 = lam[0], l1 = lam[1];
    {
        u16x8 raw = *(const u16x8*)&qkvb[(size_t)t * 3072 + 2048 + h * 32 + dg * 8];
        const float4* vep = (const float4*)&ve[(size_t)t * 1024 + h * 32 + dg * 8];
        float4 a = vep[0], b = vep[1];
        float vef[8] = {a.x, a.y, a.z, a.w, b.x, b.y, b.z, b.w};
        #pragma unroll
        for (int j = 0; j < 8; ++j)
            vtile[(dg * 8 + j) * 65 + tl] = l0 * bf2f(raw[j]) + l1 * vef[j];
    }
    __syncthreads();
    {
        const int d = tid >> 3, jj = tid & 7;
        u16x8 o;
        #pragma unroll
        for (int e = 0; e < 8; ++e)
            o[e] = f2bfn(vtile[d * 65 + jj * 8 + e]);
        *(u16x8*)&vtb[((size_t)h * HD_ + d) * TSEQ + t0 + jj * 8] = o;
    }
}

// ---------------- causal flash attention ----------------
// Fixed-point softmax: scores bounded (|s| <= 5.6 in log2 domain since ||q||=||k||=sqrt(32),
// SCALE*log2e folded into q) -> P = exp2(s) directly, no max tracking, constant cancels in p/sum(p).
// One key-tile step for one chain. s = mfma(K,Q) -> S^T: col(l15)=q, row(16ni+4hi+r)=key.
template<bool MASK>
__device__ __forceinline__ void chain_step(const bf16x8* kf, const bf16x8* vv0, const bf16x8* vv1,
                                           ushort_t* pb, const bf16x8& qf,
                                           int kb0, int qrow, int l15, int hi,
                                           f32x4& a0, f32x4& a1, float& lp)
{
    f32x4 s[4];
    #pragma unroll
    for (int ni = 0; ni < 4; ++ni){
        f32x4 z = {0.f, 0.f, 0.f, 0.f};
        s[ni] = __builtin_amdgcn_mfma_f32_16x16x32_bf16(kf[ni], qf, z, 0, 0, 0);
    }
    if (MASK){
        const int relc = qrow - kb0 - 4 * hi;
        #pragma unroll
        for (int ni = 0; ni < 4; ++ni)
            #pragma unroll
            for (int r = 0; r < 4; ++r)
                if (16 * ni + r > relc) s[ni][r] = -1e30f;
    }
    float ps = 0.f;
    #pragma unroll
    for (int ni = 0; ni < 4; ++ni)
        #pragma unroll
        for (int r = 0; r < 4; ++r){
            float p = fexp2(s[ni][r]);
            s[ni][r] = p;
            ps += p;
        }
    lp += ps;                                   // per-lane partial rowsum (16 keys)
    #pragma unroll
    for (int ni = 0; ni < 4; ++ni){
        ushort4 pk;
        pk.x = f2bfn(s[ni][0]); pk.y = f2bfn(s[ni][1]);
        pk.z = f2bfn(s[ni][2]); pk.w = f2bfn(s[ni][3]);
        *(ushort4*)&pb[l15 * 72 + ni * 16 + hi * 4] = pk;
    }
    #pragma unroll
    for (int kk = 0; kk < 2; ++kk){
        bf16x8 pf = *(const bf16x8*)&pb[l15 * 72 + kk * 32 + hi * 8];
        a0 = __builtin_amdgcn_mfma_f32_16x16x32_bf16(vv0[kk], pf, a0, 0, 0, 0);
        a1 = __builtin_amdgcn_mfma_f32_16x16x32_bf16(vv1[kk], pf, a1, 0, 0, 0);
    }
}

// grid 512: bid -> xcd=bid&7 hosts heads [4*xcd, 4*xcd+4) (per-XCD working set ~1.5MB < 4MB L2).
// Block: head h, q-tile pair {b, 31-b} (64 rows each). 4 waves, wave w owns strip w of BOTH tiles.
// K/V staged to LDS (double-buffered, XOR-swizzled), shared by all waves and both chains.
__global__ __launch_bounds__(256) void k_attn(const ushort_t* __restrict__ qb,
                                              const ushort_t* __restrict__ kb,
                                              const ushort_t* __restrict__ vtb,
                                              ushort_t* __restrict__ yb)
{
    const int bid = blockIdx.x;
    const int xcd = bid & 7, idx = bid >> 3;
    const int h = xcd * 4 + (idx >> 4);
    const int b = idx & 15;
    const int tid = threadIdx.x;
    const int w = tid >> 6, lane = tid & 63;
    const int l15 = lane & 15, hi = lane >> 4;

    __shared__ __align__(16) ushort_t Kbuf[2][64 * 32];     // [key][d], row 64B, slot-XOR swizzled
    __shared__ __align__(16) ushort_t Vbuf[2][32 * 64];     // [d][key], row 128B, slot-XOR swizzled
    __shared__ __align__(16) ushort_t Pbuf[4][2][16 * 72];  // per-wave, per-chain

    const ushort_t* kb_h = kb + (size_t)h * TSEQ * HD_;
    const ushort_t* vt_h = vtb + (size_t)h * HD_ * TSEQ;
    const ushort_t* qb_h = qb + (size_t)h * TSEQ * HD_;

    const int qtA = b, qtB = 31 - b;
    const int qwA = qtA * 64 + w * 16, qwB = qtB * 64 + w * 16;
    const bf16x8 qfA = *(const bf16x8*)&qb_h[(size_t)(qwA + l15) * 32 + hi * 8];
    const bf16x8 qfB = *(const bf16x8*)&qb_h[(size_t)(qwB + l15) * 32 + hi * 8];

    // staging lane->src mapping (pre-swizzled source, linear LDS dest; rule #21)
    const int krow_in = w * 16 + (lane >> 2);               // K chunk w: rows 16w..16w+15
    const int kslot_in = (lane & 3) ^ ((krow_in >> 1) & 3);
    const int vrow_in = w * 8 + (lane >> 3);                // V chunk w: d rows 8w..8w+7
    const int vslot_in = (lane & 7) ^ (vrow_in & 7);

    auto stage = [&](int kt, int buf){
        int kb0 = kt * 64;
        gld16(&kb_h[(size_t)(kb0 + krow_in) * 32 + kslot_in * 8], &Kbuf[buf][w * 512]);
        gld16(&vt_h[(size_t)vrow_in * TSEQ + kb0 + vslot_in * 8], &Vbuf[buf][w * 512]);
    };

    const int kswz = hi ^ ((l15 >> 1) & 3);                 // K read slot
    const int vswz = l15 & 7;                               // V read slot xor

    f32x4 a0A = {0.f,0.f,0.f,0.f}, a1A = a0A, a0B = a0A, a1B = a0A;
    float lpA = 0.f, lpB = 0.f;
    ushort_t* pbB = &Pbuf[w][0][0];
    ushort_t* pbA = &Pbuf[w][1][0];

    stage(0, 0);
    int cur = 0;
    const int nB = qtB + 1;
    for (int kt = 0; kt < nB; ++kt){
        __syncthreads();                        // drains prev stage (vmcnt) + all ds (lgkm)
        if (kt + 1 < nB) stage(kt + 1, cur ^ 1);
        const int kb0 = kt * 64;
        bf16x8 kf[4], vv0[2], vv1[2];
        #pragma unroll
        for (int ni = 0; ni < 4; ++ni)
            kf[ni] = *(const bf16x8*)&Kbuf[cur][(16 * ni + l15) * 32 + kswz * 8];
        #pragma unroll
        for (int kk = 0; kk < 2; ++kk){
            vv0[kk] = *(const bf16x8*)&Vbuf[cur][l15 * 64 + ((kk * 4 + hi) ^ vswz) * 8];
            vv1[kk] = *(const bf16x8*)&Vbuf[cur][(16 + l15) * 64 + ((kk * 4 + hi) ^ vswz) * 8];
        }
        if (kt < qtB)
            chain_step<false>(kf, vv0, vv1, pbB, qfB, kb0, qwB + l15, l15, hi, a0B, a1B, lpB);
        else
            chain_step<true >(kf, vv0, vv1, pbB, qfB, kb0, qwB + l15, l15, hi, a0B, a1B, lpB);
        if (kt < qtA)
            chain_step<false>(kf, vv0, vv1, pbA, qfA, kb0, qwA + l15, l15, hi, a0A, a1A, lpA);
        else if (kt == qtA)
            chain_step<true >(kf, vv0, vv1, pbA, qfA, kb0, qwA + l15, l15, hi, a0A, a1A, lpA);
        cur ^= 1;
    }

    #pragma unroll
    for (int which = 0; which < 2; ++which){
        f32x4 a0 = which ? a0B : a0A;
        f32x4 a1 = which ? a1B : a1A;
        float lp = which ? lpB : lpA;
        int qw = which ? qwB : qwA;
        lp += __shfl_xor(lp, 16);
        lp += __shfl_xor(lp, 32);
        float inv = 1.0f / lp;
        ushort4 o0, o1;
        o0.x = f2bfn(a0[0]*inv); o0.y = f2bfn(a0[1]*inv);
        o0.z = f2bfn(a0[2]*inv); o0.w = f2bfn(a0[3]*inv);
        o1.x = f2bfn(a1[0]*inv); o1.y = f2bfn(a1[1]*inv);
        o1.z = f2bfn(a1[2]*inv); o1.w = f2bfn(a1[3]*inv);
        size_t base = (size_t)(qw + l15) * 1024 + h * 32;
        *(ushort4*)&yb[base + hi * 4]      = o0;
        *(ushort4*)&yb[base + 16 + hi * 4] = o1;
    }
}

// ---------------- launcher ----------------
extern "C" void kernel_launch(void* const* d_in, const int* in_sizes, int n_in,
                              void* d_out, int out_size, void* d_ws, size_t ws_size,
                              hipStream_t stream)
{
    const float* x   = (const float*)d_in[0];
    const float* ve  = (const float*)d_in[1];
    const float* qkw = (const float*)d_in[2];
    const float* lam = (const float*)d_in[3];
    const float* cpw = (const float*)d_in[4];

    char* ws = (char*)d_ws;
    size_t o = 0;
    auto take = [&](size_t bytes) -> char* {
        char* p = ws + o; o += (bytes + 255) & ~(size_t)255; return p;
    };
    ushort_t* xb   = (ushort_t*)take((size_t)TSEQ * 1024 * 2);
    ushort_t* wb   = (ushort_t*)take((size_t)3072 * 1024 * 2);
    ushort_t* cpb  = (ushort_t*)take((size_t)1024 * 1024 * 2);
    ushort_t* qkvb = (ushort_t*)take((size_t)TSEQ * 3072 * 2);
    float*    cost = (float*)take((size_t)TSEQ * 16 * 4);
    float*    sint = (float*)take((size_t)TSEQ * 16 * 4);
    ushort_t* qb   = (ushort_t*)take((size_t)NHEADS * TSEQ * HD_ * 2);
    ushort_t* kb   = (ushort_t*)take((size_t)NHEADS * TSEQ * HD_ * 2);
    ushort_t* vtb  = (ushort_t*)take((size_t)NHEADS * HD_ * TSEQ * 2);
    ushort_t* yb   = xb;  // xb dead after QKV GEMM; reuse for y

    const int prep_items = (TSEQ * 1024 + 3 * 1024 * 1024 + 1024 * 1024) / 4 + TSEQ * 16;
    k_prep<<<(prep_items + 255) / 256, 256, 0, stream>>>(x, qkw, cpw, xb, wb, cpb, cost, sint);
    k_gemm64<64, 128, true ><<<dim3(3072 / 128, TSEQ / 64), 256, 0, stream>>>(xb, wb, qkvb, TSEQ, 3072, 1024);
    k_fuse<<<dim3(TSEQ / 64, NHEADS), 256, 0, stream>>>(qkvb, ve, lam, cost, sint, qb, kb, vtb);
    k_attn<<<512, 256, 0, stream>>>(qb, kb, vtb, yb);
    k_gemm64<64, 64, false><<<dim3(1024 / 64, TSEQ / 64), 256, 0, stream>>>(yb, cpb, (float*)d_out, TSEQ, 1024, 1024);
}

// Round 5
// 159.301 us; speedup vs baseline: 1.4858x; 1.0137x over previous
//
#include <hip/hip_runtime.h>
#include <hip/hip_bf16.h>

#define NHEADS 32
#define HD_ 32
#define TSEQ 2048
#define SCALE_ 0.12f
#define LOG2E_ 1.44269504088896f
#define RMS_EPS_ 1.1920929e-07f

typedef unsigned short ushort_t;
typedef __bf16 bf16_t;
typedef __attribute__((ext_vector_type(8))) bf16_t bf16x8;
typedef __attribute__((ext_vector_type(4))) float f32x4;
typedef __attribute__((ext_vector_type(8))) unsigned short u16x8;

__device__ __forceinline__ ushort_t f2bfn(float f){
    __hip_bfloat16 b = __float2bfloat16(f);
    return *reinterpret_cast<ushort_t*>(&b);
}
__device__ __forceinline__ float bf2f(ushort_t s){
    union { unsigned u; float f; } v; v.u = ((unsigned)s) << 16;
    return v.f;
}
__device__ __forceinline__ float fexp2(float x){
#if __has_builtin(__builtin_amdgcn_exp2f)
    return __builtin_amdgcn_exp2f(x);
#else
    return exp2f(x);
#endif
}
__device__ __forceinline__ void gld16(const void* g, void* l){
    __builtin_amdgcn_global_load_lds(
        (const __attribute__((address_space(1))) unsigned int*)g,
        (__attribute__((address_space(3))) unsigned int*)l,
        16, 0, 0);
}

// ---------------- prep: fp32->bf16 converts + rotary tables ----------------
__global__ __launch_bounds__(256) void k_prep(const float* __restrict__ x,
                                              const float* __restrict__ qkw,
                                              const float* __restrict__ cpw,
                                              ushort_t* __restrict__ xb,
                                              ushort_t* __restrict__ wb,
                                              ushort_t* __restrict__ cpb,
                                              float* __restrict__ cost,
                                              float* __restrict__ sint)
{
    const int n1 = TSEQ * 1024 / 4, n2 = 3 * 1024 * 1024 / 4, n3 = 1024 * 1024 / 4;
    int i = blockIdx.x * 256 + threadIdx.x;
    if (i < n1 + n2 + n3){
        const float* src; ushort_t* dst; int j = i;
        if (j < n1){ src = x; dst = xb; }
        else if (j < n1 + n2){ j -= n1; src = qkw; dst = wb; }
        else { j -= n1 + n2; src = cpw; dst = cpb; }
        float4 v = ((const float4*)src)[j];
        ushort4 o;
        o.x = f2bfn(v.x); o.y = f2bfn(v.y); o.z = f2bfn(v.z); o.w = f2bfn(v.w);
        ((ushort4*)dst)[j] = o;
    } else {
        int g = i - (n1 + n2 + n3);
        if (g < TSEQ * 16){
            int t = g >> 4, ii = g & 15;
            float c = 1.0f, s = 0.0f;
            if (ii < 8){
                float af = powf(1.0f / 128.0f, (float)ii * (1.0f / 7.0f));
                sincosf((float)t * af, &s, &c);
            }
            cost[g] = c; sint[g] = s;
        }
    }
}

// ---------------- QKV GEMM: 128x128 tile, BK=32, double-buffered (m97 ratio) ----------------
__global__ __launch_bounds__(256, 3) void k_gemm128(const ushort_t* __restrict__ A,
                                                    const ushort_t* __restrict__ B,
                                                    ushort_t* __restrict__ C,
                                                    int M, int N, int K)
{
    __shared__ __align__(16) ushort_t As[2][128 * 32];
    __shared__ __align__(16) ushort_t Bs[2][128 * 32];
    const int tid = threadIdx.x;
    const int lane = tid & 63;
    const int w = tid >> 6;
    const int wr = w >> 1, wc = w & 1;
    const int l15 = lane & 15, hi = lane >> 4;
    const int m0 = blockIdx.y * 128, n0 = blockIdx.x * 128;
    const int srow = lane >> 2, scol = (lane & 3) * 8;   // 16 rows x 64B per 1KB chunk

    f32x4 acc[4][4] = {};

    auto stage = [&](int k0, int buf){
        #pragma unroll
        for (int i = 0; i < 2; ++i){
            int c = w * 2 + i;
            gld16(&A[(size_t)(m0 + c * 16 + srow) * K + k0 + scol], &As[buf][c * 512]);
            gld16(&B[(size_t)(n0 + c * 16 + srow) * K + k0 + scol], &Bs[buf][c * 512]);
        }
    };

    stage(0, 0);
    int cur = 0;
    for (int k0 = 0; k0 < K; k0 += 32){
        __syncthreads();                          // drains vmcnt (stage) + lgkm
        if (k0 + 32 < K) stage(k0 + 32, cur ^ 1); // prefetch overlaps compute below
        bf16x8 af[4], bfr[4];
        #pragma unroll
        for (int mi = 0; mi < 4; ++mi)
            af[mi] = *(const bf16x8*)&As[cur][(wr * 64 + mi * 16 + l15) * 32 + hi * 8];
        #pragma unroll
        for (int ni = 0; ni < 4; ++ni)
            bfr[ni] = *(const bf16x8*)&Bs[cur][(wc * 64 + ni * 16 + l15) * 32 + hi * 8];
        #pragma unroll
        for (int mi = 0; mi < 4; ++mi)
            #pragma unroll
            for (int ni = 0; ni < 4; ++ni)
                acc[mi][ni] = __builtin_amdgcn_mfma_f32_16x16x32_bf16(af[mi], bfr[ni], acc[mi][ni], 0, 0, 0);
        cur ^= 1;
    }

    #pragma unroll
    for (int mi = 0; mi < 4; ++mi)
        #pragma unroll
        for (int ni = 0; ni < 4; ++ni)
            #pragma unroll
            for (int r = 0; r < 4; ++r){
                int row = m0 + wr * 64 + mi * 16 + hi * 4 + r;
                int col = n0 + wc * 64 + ni * 16 + l15;
                C[(size_t)row * N + col] = f2bfn(acc[mi][ni][r]);
            }
}

// ---------------- out-proj GEMM: 64x64, BK=64, double-buffered ----------------
__global__ __launch_bounds__(256) void k_gemm_out(const ushort_t* __restrict__ A,
                                                  const ushort_t* __restrict__ B,
                                                  float* __restrict__ C,
                                                  int M, int N, int K)
{
    __shared__ __align__(16) ushort_t As[2][64 * 64];
    __shared__ __align__(16) ushort_t Bs[2][64 * 64];
    const int tid = threadIdx.x;
    const int lane = tid & 63;
    const int w = tid >> 6;
    const int wr = w >> 1, wc = w & 1;
    const int l15 = lane & 15, hi = lane >> 4;
    const int m0 = blockIdx.y * 64, n0 = blockIdx.x * 64;
    const int srow = lane >> 3, scol = (lane & 7) * 8;   // 8 rows x 128B per 1KB chunk

    f32x4 acc[2][2] = {};

    auto stage = [&](int k0, int buf){
        #pragma unroll
        for (int i = 0; i < 2; ++i){
            int c = w * 2 + i;
            gld16(&A[(size_t)(m0 + c * 8 + srow) * K + k0 + scol], &As[buf][c * 512]);
            gld16(&B[(size_t)(n0 + c * 8 + srow) * K + k0 + scol], &Bs[buf][c * 512]);
        }
    };

    stage(0, 0);
    int cur = 0;
    for (int k0 = 0; k0 < K; k0 += 64){
        __syncthreads();
        if (k0 + 64 < K) stage(k0 + 64, cur ^ 1);
        bf16x8 af[2][2], bfr[2][2];
        #pragma unroll
        for (int mi = 0; mi < 2; ++mi)
            #pragma unroll
            for (int sub = 0; sub < 2; ++sub)
                af[mi][sub] = *(const bf16x8*)&As[cur][(wr * 32 + mi * 16 + l15) * 64 + sub * 32 + hi * 8];
        #pragma unroll
        for (int ni = 0; ni < 2; ++ni)
            #pragma unroll
            for (int sub = 0; sub < 2; ++sub)
                bfr[ni][sub] = *(const bf16x8*)&Bs[cur][(wc * 32 + ni * 16 + l15) * 64 + sub * 32 + hi * 8];
        #pragma unroll
        for (int sub = 0; sub < 2; ++sub)
            #pragma unroll
            for (int mi = 0; mi < 2; ++mi)
                #pragma unroll
                for (int ni = 0; ni < 2; ++ni)
                    acc[mi][ni] = __builtin_amdgcn_mfma_f32_16x16x32_bf16(af[mi][sub], bfr[ni][sub], acc[mi][ni], 0, 0, 0);
        cur ^= 1;
    }

    #pragma unroll
    for (int mi = 0; mi < 2; ++mi)
        #pragma unroll
        for (int ni = 0; ni < 2; ++ni)
            #pragma unroll
            for (int r = 0; r < 4; ++r){
                int row = m0 + wr * 32 + mi * 16 + hi * 4 + r;
                int col = n0 + wc * 32 + ni * 16 + l15;
                C[(size_t)row * N + col] = acc[mi][ni][r];
            }
}

// ---------------- fuse: RMSNorm + rotary (SCALE*log2e into q), v-mix, V transpose ----------------
__global__ __launch_bounds__(256) void k_fuse(const ushort_t* __restrict__ qkvb,
                                              const float* __restrict__ ve,
                                              const float* __restrict__ lam,
                                              const float* __restrict__ cost,
                                              const float* __restrict__ sint,
                                              ushort_t* __restrict__ qb,
                                              ushort_t* __restrict__ kb,
                                              ushort_t* __restrict__ vtb)
{
    const int h  = blockIdx.y;
    const int t0 = blockIdx.x * 64;
    const int tid = threadIdx.x;
    const int tl = tid >> 2;
    const int dg = tid & 3;
    const int t  = t0 + tl;

    __shared__ __align__(16) float vtile[32 * 65];

    float cs[8], sn[8];
    #pragma unroll
    for (int j = 0; j < 8; ++j){
        int ci = (dg * 8 + j) & 15;
        cs[j] = cost[t * 16 + ci];
        sn[j] = sint[t * 16 + ci];
    }
    const float sgn = (dg < 2) ? 1.0f : -1.0f;

    #pragma unroll
    for (int which = 0; which < 2; ++which){
        u16x8 raw = *(const u16x8*)&qkvb[(size_t)t * 3072 + which * 1024 + h * 32 + dg * 8];
        float v[8];
        float ss = 0.0f;
        #pragma unroll
        for (int j = 0; j < 8; ++j){ v[j] = bf2f(raw[j]); ss += v[j] * v[j]; }
        ss += __shfl_xor(ss, 1);
        ss += __shfl_xor(ss, 2);
        const float inv = rsqrtf(ss * (1.0f / 32.0f) + RMS_EPS_);
        const float scl = (which == 0) ? SCALE_ * LOG2E_ : 1.0f;
        u16x8 o;
        #pragma unroll
        for (int j = 0; j < 8; ++j){
            float nv = v[j] * inv;
            float p  = __shfl_xor(nv, 2);
            o[j] = f2bfn((nv * cs[j] + sgn * p * sn[j]) * scl);
        }
        ushort_t* dst = (which == 0) ? qb : kb;
        *(u16x8*)&dst[((size_t)h * TSEQ + t) * 32 + dg * 8] = o;
    }

    const float l0 = lam[0], l1 = lam[1];
    {
        u16x8 raw = *(const u16x8*)&qkvb[(size_t)t * 3072 + 2048 + h * 32 + dg * 8];
        const float4* vep = (const float4*)&ve[(size_t)t * 1024 + h * 32 + dg * 8];
        float4 a = vep[0], b = vep[1];
        float vef[8] = {a.x, a.y, a.z, a.w, b.x, b.y, b.z, b.w};
        #pragma unroll
        for (int j = 0; j < 8; ++j)
            vtile[(dg * 8 + j) * 65 + tl] = l0 * bf2f(raw[j]) + l1 * vef[j];
    }
    __syncthreads();
    {
        const int d = tid >> 3, jj = tid & 7;
        u16x8 o;
        #pragma unroll
        for (int e = 0; e < 8; ++e)
            o[e] = f2bfn(vtile[d * 65 + jj * 8 + e]);
        *(u16x8*)&vtb[((size_t)h * HD_ + d) * TSEQ + t0 + jj * 8] = o;
    }
}

// ---------------- causal flash attention, KVBLK=128 ----------------
// No-max softmax: ||q||=||k||=sqrt(32), SCALE*log2e in q -> |s| <= 5.6 -> P=exp2(s) raw.
template<bool MASK>
__device__ __forceinline__ void chain_step(const bf16x8* kf, const bf16x8* vv0, const bf16x8* vv1,
                                           ushort_t* pb, const bf16x8& qf,
                                           int kb0, int qrow, int l15, int hi,
                                           f32x4& a0, f32x4& a1, float& lp)
{
    f32x4 s[4];
    __builtin_amdgcn_s_setprio(1);
    #pragma unroll
    for (int ni = 0; ni < 4; ++ni){
        f32x4 z = {0.f, 0.f, 0.f, 0.f};
        s[ni] = __builtin_amdgcn_mfma_f32_16x16x32_bf16(kf[ni], qf, z, 0, 0, 0);  // S^T
    }
    __builtin_amdgcn_s_setprio(0);
    if (MASK){
        const int relc = qrow - kb0 - 4 * hi;
        #pragma unroll
        for (int ni = 0; ni < 4; ++ni)
            #pragma unroll
            for (int r = 0; r < 4; ++r)
                if (16 * ni + r > relc) s[ni][r] = -1e30f;
    }
    float ps = 0.f;
    #pragma unroll
    for (int ni = 0; ni < 4; ++ni)
        #pragma unroll
        for (int r = 0; r < 4; ++r){
            float p = fexp2(s[ni][r]);
            s[ni][r] = p;
            ps += p;
        }
    lp += ps;
    #pragma unroll
    for (int ni = 0; ni < 4; ++ni){
        ushort4 pk;
        pk.x = f2bfn(s[ni][0]); pk.y = f2bfn(s[ni][1]);
        pk.z = f2bfn(s[ni][2]); pk.w = f2bfn(s[ni][3]);
        *(ushort4*)&pb[l15 * 72 + ni * 16 + hi * 4] = pk;
    }
    __builtin_amdgcn_s_setprio(1);
    #pragma unroll
    for (int kk = 0; kk < 2; ++kk){
        bf16x8 pf = *(const bf16x8*)&pb[l15 * 72 + kk * 32 + hi * 8];
        a0 = __builtin_amdgcn_mfma_f32_16x16x32_bf16(vv0[kk], pf, a0, 0, 0, 0);
        a1 = __builtin_amdgcn_mfma_f32_16x16x32_bf16(vv1[kk], pf, a1, 0, 0, 0);
    }
    __builtin_amdgcn_s_setprio(0);
}

// grid 512: xcd=bid&7 -> heads [4*xcd,4*xcd+4) (per-XCD K/V ~1.5MB < 4MB L2).
// Block: head h, q-tile pair {b, 31-b}. 4 waves; K/V 128-key tiles double-buffered in LDS.
__global__ __launch_bounds__(256) void k_attn(const ushort_t* __restrict__ qb,
                                              const ushort_t* __restrict__ kb,
                                              const ushort_t* __restrict__ vtb,
                                              ushort_t* __restrict__ yb)
{
    const int bid = blockIdx.x;
    const int xcd = bid & 7, idx = bid >> 3;
    const int h = xcd * 4 + (idx >> 4);
    const int b = idx & 15;
    const int tid = threadIdx.x;
    const int w = tid >> 6, lane = tid & 63;
    const int l15 = lane & 15, hi = lane >> 4;

    __shared__ __align__(16) ushort_t Kbuf[2][128 * 32];   // [key][d], 64B rows, linear
    __shared__ __align__(16) ushort_t Vbuf[2][32 * 128];   // [d][key], 256B rows, slot-XOR swz
    __shared__ __align__(16) ushort_t Pbuf[4][16 * 72];    // per-wave, shared by chains

    const ushort_t* kb_h = kb + (size_t)h * TSEQ * HD_;
    const ushort_t* vt_h = vtb + (size_t)h * HD_ * TSEQ;
    const ushort_t* qb_h = qb + (size_t)h * TSEQ * HD_;

    const int qtA = b, qtB = 31 - b;
    const int qwA = qtA * 64 + w * 16, qwB = qtB * 64 + w * 16;
    const bf16x8 qfA = *(const bf16x8*)&qb_h[(size_t)(qwA + l15) * 32 + hi * 8];
    const bf16x8 qfB = *(const bf16x8*)&qb_h[(size_t)(qwB + l15) * 32 + hi * 8];

    // staging (linear LDS dest; V source pre-permuted by the same involution used on read)
    const int kck0 = w * 2;                                 // chunks 2w, 2w+1
    auto stage = [&](int bs, int buf){
        const int kb0 = bs * 128;
        #pragma unroll
        for (int i = 0; i < 2; ++i){
            int c = kck0 + i;
            int krow = c * 16 + (lane >> 2);
            gld16(&kb_h[(size_t)(kb0 + krow) * 32 + (lane & 3) * 8], &Kbuf[buf][c * 512]);
            int vrow = c * 4 + (lane >> 4);
            int vj = (lane & 15) ^ (vrow & 7);
            gld16(&vt_h[(size_t)vrow * TSEQ + kb0 + vj * 8], &Vbuf[buf][c * 512]);
        }
    };

    f32x4 a0A = {0.f,0.f,0.f,0.f}, a1A = a0A, a0B = a0A, a1B = a0A;
    float lpA = 0.f, lpB = 0.f;
    ushort_t* pb = &Pbuf[w][0];

    const int nA = qtA + 1, nB = qtB + 1;
    const int NB2 = (nB + 1) >> 1;

    stage(0, 0);
    int cur = 0;
    for (int bs = 0; bs < NB2; ++bs){
        __syncthreads();                        // drains stage vmcnt + all lgkm
        if (bs + 1 < NB2) stage(bs + 1, cur ^ 1);
        #pragma unroll
        for (int sub = 0; sub < 2; ++sub){
            const int kt = bs * 2 + sub;
            if (kt >= nB) break;
            const int kb0 = kt * 64;
            bf16x8 kf[4], vv0[2], vv1[2];
            #pragma unroll
            for (int ni = 0; ni < 4; ++ni)
                kf[ni] = *(const bf16x8*)&Kbuf[cur][(sub * 64 + ni * 16 + l15) * 32 + hi * 8];
            #pragma unroll
            for (int kk = 0; kk < 2; ++kk){
                int sl = sub * 8 + kk * 4 + hi;
                vv0[kk] = *(const bf16x8*)&Vbuf[cur][l15 * 128 + (sl ^ (l15 & 7)) * 8];
                vv1[kk] = *(const bf16x8*)&Vbuf[cur][(16 + l15) * 128 + (sl ^ (l15 & 7)) * 8];
            }
            if (kt < qtB)
                chain_step<false>(kf, vv0, vv1, pb, qfB, kb0, qwB + l15, l15, hi, a0B, a1B, lpB);
            else
                chain_step<true >(kf, vv0, vv1, pb, qfB, kb0, qwB + l15, l15, hi, a0B, a1B, lpB);
            if (kt < qtA)
                chain_step<false>(kf, vv0, vv1, pb, qfA, kb0, qwA + l15, l15, hi, a0A, a1A, lpA);
            else if (kt == qtA)
                chain_step<true >(kf, vv0, vv1, pb, qfA, kb0, qwA + l15, l15, hi, a0A, a1A, lpA);
        }
        cur ^= 1;
    }

    #pragma unroll
    for (int which = 0; which < 2; ++which){
        f32x4 a0 = which ? a0B : a0A;
        f32x4 a1 = which ? a1B : a1A;
        float lp = which ? lpB : lpA;
        int qw = which ? qwB : qwA;
        lp += __shfl_xor(lp, 16);
        lp += __shfl_xor(lp, 32);
        float inv = 1.0f / lp;
        ushort4 o0, o1;
        o0.x = f2bfn(a0[0]*inv); o0.y = f2bfn(a0[1]*inv);
        o0.z = f2bfn(a0[2]*inv); o0.w = f2bfn(a0[3]*inv);
        o1.x = f2bfn(a1[0]*inv); o1.y = f2bfn(a1[1]*inv);
        o1.z = f2bfn(a1[2]*inv); o1.w = f2bfn(a1[3]*inv);
        size_t base = (size_t)(qw + l15) * 1024 + h * 32;
        *(ushort4*)&yb[base + hi * 4]      = o0;
        *(ushort4*)&yb[base + 16 + hi * 4] = o1;
    }
}

// ---------------- launcher ----------------
extern "C" void kernel_launch(void* const* d_in, const int* in_sizes, int n_in,
                              void* d_out, int out_size, void* d_ws, size_t ws_size,
                              hipStream_t stream)
{
    const float* x   = (const float*)d_in[0];
    const float* ve  = (const float*)d_in[1];
    const float* qkw = (const float*)d_in[2];
    const float* lam = (const float*)d_in[3];
    const float* cpw = (const float*)d_in[4];

    char* ws = (char*)d_ws;
    size_t o = 0;
    auto take = [&](size_t bytes) -> char* {
        char* p = ws + o; o += (bytes + 255) & ~(size_t)255; return p;
    };
    ushort_t* xb   = (ushort_t*)take((size_t)TSEQ * 1024 * 2);
    ushort_t* wb   = (ushort_t*)take((size_t)3072 * 1024 * 2);
    ushort_t* cpb  = (ushort_t*)take((size_t)1024 * 1024 * 2);
    ushort_t* qkvb = (ushort_t*)take((size_t)TSEQ * 3072 * 2);
    float*    cost = (float*)take((size_t)TSEQ * 16 * 4);
    float*    sint = (float*)take((size_t)TSEQ * 16 * 4);
    ushort_t* qb   = (ushort_t*)take((size_t)NHEADS * TSEQ * HD_ * 2);
    ushort_t* kb   = (ushort_t*)take((size_t)NHEADS * TSEQ * HD_ * 2 + 8192);   // +64-token slack (staging overrun)
    ushort_t* vtb  = (ushort_t*)take((size_t)NHEADS * HD_ * TSEQ * 2 + 8192);   // +slack
    ushort_t* yb   = xb;  // xb dead after QKV GEMM; reuse for y

    const int prep_items = (TSEQ * 1024 + 3 * 1024 * 1024 + 1024 * 1024) / 4 + TSEQ * 16;
    k_prep<<<(prep_items + 255) / 256, 256, 0, stream>>>(x, qkw, cpw, xb, wb, cpb, cost, sint);
    k_gemm128<<<dim3(3072 / 128, TSEQ / 128), 256, 0, stream>>>(xb, wb, qkvb, TSEQ, 3072, 1024);
    k_fuse<<<dim3(TSEQ / 64, NHEADS), 256, 0, stream>>>(qkvb, ve, lam, cost, sint, qb, kb, vtb);
    k_attn<<<512, 256, 0, stream>>>(qb, kb, vtb, yb);
    k_gemm_out<<<dim3(1024 / 64, TSEQ / 64), 256, 0, stream>>>(yb, cpb, (float*)d_out, TSEQ, 1024, 1024);
}

// Round 7
// 153.197 us; speedup vs baseline: 1.5450x; 1.0398x over previous
//
#include <hip/hip_runtime.h>
#include <hip/hip_bf16.h>

#define NHEADS 32
#define HD_ 32
#define TSEQ 2048
#define SCALE_ 0.12f
#define LOG2E_ 1.44269504088896f
#define RMS_EPS_ 1.1920929e-07f

typedef unsigned short ushort_t;
typedef __bf16 bf16_t;
typedef __attribute__((ext_vector_type(8))) bf16_t bf16x8;
typedef __attribute__((ext_vector_type(4))) float f32x4;
typedef __attribute__((ext_vector_type(8))) unsigned short u16x8;

__device__ __forceinline__ ushort_t f2bfn(float f){
    __hip_bfloat16 b = __float2bfloat16(f);
    return *reinterpret_cast<ushort_t*>(&b);
}
__device__ __forceinline__ float bf2f(ushort_t s){
    union { unsigned u; float f; } v; v.u = ((unsigned)s) << 16;
    return v.f;
}
__device__ __forceinline__ float fexp2(float x){
#if __has_builtin(__builtin_amdgcn_exp2f)
    return __builtin_amdgcn_exp2f(x);
#else
    return exp2f(x);
#endif
}
__device__ __forceinline__ void gld16(const void* g, void* l){
    __builtin_amdgcn_global_load_lds(
        (const __attribute__((address_space(1))) unsigned int*)g,
        (__attribute__((address_space(3))) unsigned int*)l,
        16, 0, 0);
}

// ---------------- prep: fp32->bf16 converts + rotary tables ----------------
__global__ __launch_bounds__(256) void k_prep(const float* __restrict__ x,
                                              const float* __restrict__ qkw,
                                              const float* __restrict__ cpw,
                                              ushort_t* __restrict__ xb,
                                              ushort_t* __restrict__ wb,
                                              ushort_t* __restrict__ cpb,
                                              float* __restrict__ cost,
                                              float* __restrict__ sint)
{
    const int n1 = TSEQ * 1024 / 4, n2 = 3 * 1024 * 1024 / 4, n3 = 1024 * 1024 / 4;
    int i = blockIdx.x * 256 + threadIdx.x;
    if (i < n1 + n2 + n3){
        const float* src; ushort_t* dst; int j = i;
        if (j < n1){ src = x; dst = xb; }
        else if (j < n1 + n2){ j -= n1; src = qkw; dst = wb; }
        else { j -= n1 + n2; src = cpw; dst = cpb; }
        float4 v = ((const float4*)src)[j];
        ushort4 o;
        o.x = f2bfn(v.x); o.y = f2bfn(v.y); o.z = f2bfn(v.z); o.w = f2bfn(v.w);
        ((ushort4*)dst)[j] = o;
    } else {
        int g = i - (n1 + n2 + n3);
        if (g < TSEQ * 16){
            int t = g >> 4, ii = g & 15;
            float c = 1.0f, s = 0.0f;
            if (ii < 8){
                float af = powf(1.0f / 128.0f, (float)ii * (1.0f / 7.0f));
                sincosf((float)t * af, &s, &c);
            }
            cost[g] = c; sint[g] = s;
        }
    }
}

// ---------------- QKV GEMM + fused epilogue ----------------
// BM=128, BN=64 (wave quadrant = 64 rows x 32 cols = exactly one head), BK=32, dbuf.
// grid (48,16) = 768 blocks = 3/CU. bx<16: q-section; <32: k; <48: v.
// Epilogue on fp32 acc: q/k -> RMSNorm + rotary (+SCALE*LOG2E into q) -> qb/kb.
//                       v   -> lam0*v + lam1*ve -> LDS transpose -> vtb[h][d][t].
__global__ __launch_bounds__(256, 3) void k_gemm_qkv(const ushort_t* __restrict__ A,
                                                     const ushort_t* __restrict__ B,
                                                     const float* __restrict__ ve,
                                                     const float* __restrict__ lam,
                                                     const float* __restrict__ cost,
                                                     const float* __restrict__ sint,
                                                     ushort_t* __restrict__ qb,
                                                     ushort_t* __restrict__ kbuf,
                                                     ushort_t* __restrict__ vtb)
{
    const int K = 1024;
    __shared__ __align__(16) ushort_t As[2][128 * 32];
    __shared__ __align__(16) ushort_t Bs[2][64 * 32];
    const int tid = threadIdx.x;
    const int lane = tid & 63;
    const int w = tid >> 6;
    const int wr = w >> 1, wc = w & 1;
    const int l15 = lane & 15, hi = lane >> 4;
    const int m0 = blockIdx.y * 128, n0 = blockIdx.x * 64;
    const int sec = n0 >> 10;                       // 0=q 1=k 2=v
    const int h = ((n0 & 1023) >> 5) + wc;          // head for this wave's quadrant
    const int srow = lane >> 2, scol = (lane & 3) * 8;

    f32x4 acc[4][2] = {};

    auto stage = [&](int k0, int buf){
        #pragma unroll
        for (int i = 0; i < 2; ++i){                // A: 8 chunks of 16 rows
            int c = w + i * 4;
            gld16(&A[(size_t)(m0 + c * 16 + srow) * K + k0 + scol], &As[buf][c * 512]);
        }
        gld16(&B[(size_t)(n0 + w * 16 + srow) * K + k0 + scol], &Bs[buf][w * 512]);
    };

    stage(0, 0);
    int cur = 0;
    for (int k0 = 0; k0 < K; k0 += 32){
        __syncthreads();
        if (k0 + 32 < K) stage(k0 + 32, cur ^ 1);
        bf16x8 af[4], bfr[2];
        #pragma unroll
        for (int mi = 0; mi < 4; ++mi)
            af[mi] = *(const bf16x8*)&As[cur][(wr * 64 + mi * 16 + l15) * 32 + hi * 8];
        #pragma unroll
        for (int ni = 0; ni < 2; ++ni)
            bfr[ni] = *(const bf16x8*)&Bs[cur][(wc * 32 + ni * 16 + l15) * 32 + hi * 8];
        #pragma unroll
        for (int mi = 0; mi < 4; ++mi)
            #pragma unroll
            for (int ni = 0; ni < 2; ++ni)
                acc[mi][ni] = __builtin_amdgcn_mfma_f32_16x16x32_bf16(af[mi], bfr[ni], acc[mi][ni], 0, 0, 0);
        cur ^= 1;
    }

    // ---------- fused epilogue ----------
    // acc[mi][ni][r]: row t = m0 + wr*64 + mi*16 + hi*4 + r ; col d = ni*16 + l15 (within head h)
    if (sec < 2){
        ushort_t* dst = (sec == 0) ? qb : kbuf;
        const float qscl = (sec == 0) ? SCALE_ * LOG2E_ : 1.0f;
        #pragma unroll
        for (int mi = 0; mi < 4; ++mi){
            #pragma unroll
            for (int r = 0; r < 4; ++r){
                const int t = m0 + wr * 64 + mi * 16 + hi * 4 + r;
                float v0 = acc[mi][0][r], v1 = acc[mi][1][r];
                float ss = v0 * v0 + v1 * v1;
                ss += __shfl_xor(ss, 1);
                ss += __shfl_xor(ss, 2);
                ss += __shfl_xor(ss, 4);
                ss += __shfl_xor(ss, 8);                  // sum over 16 l15 lanes
                const float inv = rsqrtf(ss * (1.0f / 32.0f) + RMS_EPS_);
                const float c = cost[t * 16 + l15], s = sint[t * 16 + l15];
                const float n0v = v0 * inv, n1v = v1 * inv;
                const float o0 = (n0v * c + n1v * s) * qscl;   // d < 16
                const float o1 = (n1v * c - n0v * s) * qscl;   // d >= 16
                size_t base = ((size_t)h * TSEQ + t) * 32;
                dst[base + l15]      = f2bfn(o0);
                dst[base + 16 + l15] = f2bfn(o1);
            }
        }
    } else {
        const float l0 = lam[0], l1 = lam[1];
        __syncthreads();                                   // all waves done with As
        ushort_t* vt = &As[0][0] + w * 2048;               // 32 rows x 64 (swizzled groups)
        #pragma unroll
        for (int ni = 0; ni < 2; ++ni){
            const int d = ni * 16 + l15;
            #pragma unroll
            for (int mi = 0; mi < 4; ++mi){
                #pragma unroll
                for (int r = 0; r < 4; ++r){
                    const int t = m0 + wr * 64 + mi * 16 + hi * 4 + r;
                    const int tl = mi * 16 + hi * 4 + r;   // 0..63 within wave
                    float vef = ve[(size_t)t * 1024 + h * 32 + d];
                    float ov = l0 * acc[mi][ni][r] + l1 * vef;
                    const int g = (tl >> 3) ^ (d & 7);     // bank-swizzled 8-col group
                    vt[d * 64 + g * 8 + (tl & 7)] = f2bfn(ov);
                }
            }
        }
        __syncthreads();
        const int tc = lane & 7;                            // t-chunk within d-row
        #pragma unroll
        for (int p = 0; p < 4; ++p){
            const int d = p * 8 + (lane >> 3);
            const int g = tc ^ (d & 7);
            u16x8 o = *(const u16x8*)&vt[d * 64 + g * 8];
            *(u16x8*)&vtb[((size_t)h * HD_ + d) * TSEQ + m0 + wr * 64 + tc * 8] = o;
        }
    }
}

// ---------------- out-proj GEMM: 64x64, BK=64, double-buffered ----------------
__global__ __launch_bounds__(256) void k_gemm_out(const ushort_t* __restrict__ A,
                                                  const ushort_t* __restrict__ B,
                                                  float* __restrict__ C,
                                                  int M, int N, int K)
{
    __shared__ __align__(16) ushort_t As[2][64 * 64];
    __shared__ __align__(16) ushort_t Bs[2][64 * 64];
    const int tid = threadIdx.x;
    const int lane = tid & 63;
    const int w = tid >> 6;
    const int wr = w >> 1, wc = w & 1;
    const int l15 = lane & 15, hi = lane >> 4;
    const int m0 = blockIdx.y * 64, n0 = blockIdx.x * 64;
    const int srow = lane >> 3, scol = (lane & 7) * 8;

    f32x4 acc[2][2] = {};

    auto stage = [&](int k0, int buf){
        #pragma unroll
        for (int i = 0; i < 2; ++i){
            int c = w * 2 + i;
            gld16(&A[(size_t)(m0 + c * 8 + srow) * K + k0 + scol], &As[buf][c * 512]);
            gld16(&B[(size_t)(n0 + c * 8 + srow) * K + k0 + scol], &Bs[buf][c * 512]);
        }
    };

    stage(0, 0);
    int cur = 0;
    for (int k0 = 0; k0 < K; k0 += 64){
        __syncthreads();
        if (k0 + 64 < K) stage(k0 + 64, cur ^ 1);
        bf16x8 af[2][2], bfr[2][2];
        #pragma unroll
        for (int mi = 0; mi < 2; ++mi)
            #pragma unroll
            for (int sub = 0; sub < 2; ++sub)
                af[mi][sub] = *(const bf16x8*)&As[cur][(wr * 32 + mi * 16 + l15) * 64 + sub * 32 + hi * 8];
        #pragma unroll
        for (int ni = 0; ni < 2; ++ni)
            #pragma unroll
            for (int sub = 0; sub < 2; ++sub)
                bfr[ni][sub] = *(const bf16x8*)&Bs[cur][(wc * 32 + ni * 16 + l15) * 64 + sub * 32 + hi * 8];
        #pragma unroll
        for (int sub = 0; sub < 2; ++sub)
            #pragma unroll
            for (int mi = 0; mi < 2; ++mi)
                #pragma unroll
                for (int ni = 0; ni < 2; ++ni)
                    acc[mi][ni] = __builtin_amdgcn_mfma_f32_16x16x32_bf16(af[mi][sub], bfr[ni][sub], acc[mi][ni], 0, 0, 0);
        cur ^= 1;
    }

    #pragma unroll
    for (int mi = 0; mi < 2; ++mi)
        #pragma unroll
        for (int ni = 0; ni < 2; ++ni)
            #pragma unroll
            for (int r = 0; r < 4; ++r){
                int row = m0 + wr * 32 + mi * 16 + hi * 4 + r;
                int col = n0 + wc * 32 + ni * 16 + l15;
                C[(size_t)row * N + col] = acc[mi][ni][r];
            }
}

// ---------------- causal flash attention, KVBLK=128 ----------------
// No-max softmax: ||q||=||k||=sqrt(32), SCALE*log2e folded into q -> |s|<=5.6 -> P=exp2(s) raw.
template<bool MASK>
__device__ __forceinline__ void chain_step(const bf16x8* kf, const bf16x8* vv0, const bf16x8* vv1,
                                           ushort_t* pb, const bf16x8& qf,
                                           int kb0, int qrow, int l15, int hi,
                                           f32x4& a0, f32x4& a1, float& lp)
{
    f32x4 s[4];
    __builtin_amdgcn_s_setprio(1);
    #pragma unroll
    for (int ni = 0; ni < 4; ++ni){
        f32x4 z = {0.f, 0.f, 0.f, 0.f};
        s[ni] = __builtin_amdgcn_mfma_f32_16x16x32_bf16(kf[ni], qf, z, 0, 0, 0);  // S^T
    }
    __builtin_amdgcn_s_setprio(0);
    if (MASK){
        const int relc = qrow - kb0 - 4 * hi;
        #pragma unroll
        for (int ni = 0; ni < 4; ++ni)
            #pragma unroll
            for (int r = 0; r < 4; ++r)
                if (16 * ni + r > relc) s[ni][r] = -1e30f;
    }
    float ps = 0.f;
    #pragma unroll
    for (int ni = 0; ni < 4; ++ni)
        #pragma unroll
        for (int r = 0; r < 4; ++r){
            float p = fexp2(s[ni][r]);
            s[ni][r] = p;
            ps += p;
        }
    lp += ps;
    #pragma unroll
    for (int ni = 0; ni < 4; ++ni){
        ushort4 pk;
        pk.x = f2bfn(s[ni][0]); pk.y = f2bfn(s[ni][1]);
        pk.z = f2bfn(s[ni][2]); pk.w = f2bfn(s[ni][3]);
        *(ushort4*)&pb[l15 * 72 + ni * 16 + hi * 4] = pk;
    }
    __builtin_amdgcn_s_setprio(1);
    #pragma unroll
    for (int kk = 0; kk < 2; ++kk){
        bf16x8 pf = *(const bf16x8*)&pb[l15 * 72 + kk * 32 + hi * 8];
        a0 = __builtin_amdgcn_mfma_f32_16x16x32_bf16(vv0[kk], pf, a0, 0, 0, 0);
        a1 = __builtin_amdgcn_mfma_f32_16x16x32_bf16(vv1[kk], pf, a1, 0, 0, 0);
    }
    __builtin_amdgcn_s_setprio(0);
}

__global__ __launch_bounds__(256) void k_attn(const ushort_t* __restrict__ qb,
                                              const ushort_t* __restrict__ kb,
                                              const ushort_t* __restrict__ vtb,
                                              ushort_t* __restrict__ yb)
{
    const int bid = blockIdx.x;
    const int xcd = bid & 7, idx = bid >> 3;
    const int h = xcd * 4 + (idx >> 4);
    const int b = idx & 15;
    const int tid = threadIdx.x;
    const int w = tid >> 6, lane = tid & 63;
    const int l15 = lane & 15, hi = lane >> 4;

    __shared__ __align__(16) ushort_t Kbuf[2][128 * 32];
    __shared__ __align__(16) ushort_t Vbuf[2][32 * 128];
    __shared__ __align__(16) ushort_t Pbuf[4][16 * 72];

    const ushort_t* kb_h = kb + (size_t)h * TSEQ * HD_;
    const ushort_t* vt_h = vtb + (size_t)h * HD_ * TSEQ;
    const ushort_t* qb_h = qb + (size_t)h * TSEQ * HD_;

    const int qtA = b, qtB = 31 - b;
    const int qwA = qtA * 64 + w * 16, qwB = qtB * 64 + w * 16;
    const bf16x8 qfA = *(const bf16x8*)&qb_h[(size_t)(qwA + l15) * 32 + hi * 8];
    const bf16x8 qfB = *(const bf16x8*)&qb_h[(size_t)(qwB + l15) * 32 + hi * 8];

    const int kck0 = w * 2;
    auto stage = [&](int bs, int buf){
        const int kb0 = bs * 128;
        #pragma unroll
        for (int i = 0; i < 2; ++i){
            int c = kck0 + i;
            int krow = c * 16 + (lane >> 2);
            gld16(&kb_h[(size_t)(kb0 + krow) * 32 + (lane & 3) * 8], &Kbuf[buf][c * 512]);
            int vrow = c * 4 + (lane >> 4);
            int vj = (lane & 15) ^ (vrow & 7);
            gld16(&vt_h[(size_t)vrow * TSEQ + kb0 + vj * 8], &Vbuf[buf][c * 512]);
        }
    };

    f32x4 a0A = {0.f,0.f,0.f,0.f}, a1A = a0A, a0B = a0A, a1B = a0A;
    float lpA = 0.f, lpB = 0.f;
    ushort_t* pb = &Pbuf[w][0];

    const int nB = qtB + 1;
    const int NB2 = (nB + 1) >> 1;

    stage(0, 0);
    int cur = 0;
    for (int bs = 0; bs < NB2; ++bs){
        __syncthreads();
        if (bs + 1 < NB2) stage(bs + 1, cur ^ 1);
        #pragma unroll
        for (int sub = 0; sub < 2; ++sub){
            const int kt = bs * 2 + sub;
            if (kt >= nB) break;
            const int kb0 = kt * 64;
            bf16x8 kf[4], vv0[2], vv1[2];
            #pragma unroll
            for (int ni = 0; ni < 4; ++ni)
                kf[ni] = *(const bf16x8*)&Kbuf[cur][(sub * 64 + ni * 16 + l15) * 32 + hi * 8];
            #pragma unroll
            for (int kk = 0; kk < 2; ++kk){
                int sl = sub * 8 + kk * 4 + hi;
                vv0[kk] = *(const bf16x8*)&Vbuf[cur][l15 * 128 + (sl ^ (l15 & 7)) * 8];
                vv1[kk] = *(const bf16x8*)&Vbuf[cur][(16 + l15) * 128 + (sl ^ (l15 & 7)) * 8];
            }
            if (kt < qtB)
                chain_step<false>(kf, vv0, vv1, pb, qfB, kb0, qwB + l15, l15, hi, a0B, a1B, lpB);
            else
                chain_step<true >(kf, vv0, vv1, pb, qfB, kb0, qwB + l15, l15, hi, a0B, a1B, lpB);
            if (kt < qtA)
                chain_step<false>(kf, vv0, vv1, pb, qfA, kb0, qwA + l15, l15, hi, a0A, a1A, lpA);
            else if (kt == qtA)
                chain_step<true >(kf, vv0, vv1, pb, qfA, kb0, qwA + l15, l15, hi, a0A, a1A, lpA);
        }
        cur ^= 1;
    }

    #pragma unroll
    for (int which = 0; which < 2; ++which){
        f32x4 a0 = which ? a0B : a0A;
        f32x4 a1 = which ? a1B : a1A;
        float lp = which ? lpB : lpA;
        int qw = which ? qwB : qwA;
        lp += __shfl_xor(lp, 16);
        lp += __shfl_xor(lp, 32);
        float inv = 1.0f / lp;
        ushort4 o0, o1;
        o0.x = f2bfn(a0[0]*inv); o0.y = f2bfn(a0[1]*inv);
        o0.z = f2bfn(a0[2]*inv); o0.w = f2bfn(a0[3]*inv);
        o1.x = f2bfn(a1[0]*inv); o1.y = f2bfn(a1[1]*inv);
        o1.z = f2bfn(a1[2]*inv); o1.w = f2bfn(a1[3]*inv);
        size_t base = (size_t)(qw + l15) * 1024 + h * 32;
        *(ushort4*)&yb[base + hi * 4]      = o0;
        *(ushort4*)&yb[base + 16 + hi * 4] = o1;
    }
}

// ---------------- launcher ----------------
extern "C" void kernel_launch(void* const* d_in, const int* in_sizes, int n_in,
                              void* d_out, int out_size, void* d_ws, size_t ws_size,
                              hipStream_t stream)
{
    const float* x   = (const float*)d_in[0];
    const float* ve  = (const float*)d_in[1];
    const float* qkw = (const float*)d_in[2];
    const float* lam = (const float*)d_in[3];
    const float* cpw = (const float*)d_in[4];

    char* ws = (char*)d_ws;
    size_t o = 0;
    auto take = [&](size_t bytes) -> char* {
        char* p = ws + o; o += (bytes + 255) & ~(size_t)255; return p;
    };
    ushort_t* xb   = (ushort_t*)take((size_t)TSEQ * 1024 * 2);
    ushort_t* wb   = (ushort_t*)take((size_t)3072 * 1024 * 2);
    ushort_t* cpb  = (ushort_t*)take((size_t)1024 * 1024 * 2);
    float*    cost = (float*)take((size_t)TSEQ * 16 * 4);
    float*    sint = (float*)take((size_t)TSEQ * 16 * 4);
    ushort_t* qb   = (ushort_t*)take((size_t)NHEADS * TSEQ * HD_ * 2);
    ushort_t* kb   = (ushort_t*)take((size_t)NHEADS * TSEQ * HD_ * 2 + 8192);   // +staging slack
    ushort_t* vtb  = (ushort_t*)take((size_t)NHEADS * HD_ * TSEQ * 2 + 8192);   // +staging slack
    ushort_t* yb   = xb;  // xb dead after QKV GEMM; reuse for y

    const int prep_items = (TSEQ * 1024 + 3 * 1024 * 1024 + 1024 * 1024) / 4 + TSEQ * 16;
    k_prep<<<(prep_items + 255) / 256, 256, 0, stream>>>(x, qkw, cpw, xb, wb, cpb, cost, sint);
    k_gemm_qkv<<<dim3(48, 16), 256, 0, stream>>>(xb, wb, ve, lam, cost, sint, qb, kb, vtb);
    k_attn<<<512, 256, 0, stream>>>(qb, kb, vtb, yb);
    k_gemm_out<<<dim3(1024 / 64, TSEQ / 64), 256, 0, stream>>>(yb, cpb, (float*)d_out, TSEQ, 1024, 1024);
}

// Round 8
// 152.004 us; speedup vs baseline: 1.5571x; 1.0078x over previous
//
#include <hip/hip_runtime.h>
#include <hip/hip_bf16.h>

#define NHEADS 32
#define HD_ 32
#define TSEQ 2048
#define SCALE_ 0.12f
#define LOG2E_ 1.44269504088896f
#define RMS_EPS_ 1.1920929e-07f

typedef unsigned short ushort_t;
typedef __bf16 bf16_t;
typedef __attribute__((ext_vector_type(8))) bf16_t bf16x8;
typedef __attribute__((ext_vector_type(4))) float f32x4;
typedef __attribute__((ext_vector_type(8))) unsigned short u16x8;

__device__ __forceinline__ ushort_t f2bfn(float f){
    __hip_bfloat16 b = __float2bfloat16(f);
    return *reinterpret_cast<ushort_t*>(&b);
}
__device__ __forceinline__ float bf2f(ushort_t s){
    union { unsigned u; float f; } v; v.u = ((unsigned)s) << 16;
    return v.f;
}
__device__ __forceinline__ float fexp2(float x){
#if __has_builtin(__builtin_amdgcn_exp2f)
    return __builtin_amdgcn_exp2f(x);
#else
    return exp2f(x);
#endif
}
__device__ __forceinline__ void gld16(const void* g, void* l){
    __builtin_amdgcn_global_load_lds(
        (const __attribute__((address_space(1))) unsigned int*)g,
        (__attribute__((address_space(3))) unsigned int*)l,
        16, 0, 0);
}

// ---------------- prep: fp32->bf16 converts + rotary tables ----------------
__global__ __launch_bounds__(256) void k_prep(const float* __restrict__ x,
                                              const float* __restrict__ qkw,
                                              const float* __restrict__ cpw,
                                              ushort_t* __restrict__ xb,
                                              ushort_t* __restrict__ wb,
                                              ushort_t* __restrict__ cpb,
                                              float* __restrict__ cost,
                                              float* __restrict__ sint)
{
    const int n1 = TSEQ * 1024 / 4, n2 = 3 * 1024 * 1024 / 4, n3 = 1024 * 1024 / 4;
    int i = blockIdx.x * 256 + threadIdx.x;
    if (i < n1 + n2 + n3){
        const float* src; ushort_t* dst; int j = i;
        if (j < n1){ src = x; dst = xb; }
        else if (j < n1 + n2){ j -= n1; src = qkw; dst = wb; }
        else { j -= n1 + n2; src = cpw; dst = cpb; }
        float4 v = ((const float4*)src)[j];
        ushort4 o;
        o.x = f2bfn(v.x); o.y = f2bfn(v.y); o.z = f2bfn(v.z); o.w = f2bfn(v.w);
        ((ushort4*)dst)[j] = o;
    } else {
        int g = i - (n1 + n2 + n3);
        if (g < TSEQ * 16){
            int t = g >> 4, ii = g & 15;
            float c = 1.0f, s = 0.0f;
            if (ii < 8){
                float af = powf(1.0f / 128.0f, (float)ii * (1.0f / 7.0f));
                sincosf((float)t * af, &s, &c);
            }
            cost[g] = c; sint[g] = s;
        }
    }
}

// ---------------- QKV GEMM + fused epilogue ----------------
// BM=128, BN=64 (wave quadrant = 64 rows x 32 cols = exactly one head), BK=32, dbuf.
// grid (48,16) = 768 blocks = 3/CU. bx<16: q-section; <32: k; <48: v.
__global__ __launch_bounds__(256, 3) void k_gemm_qkv(const ushort_t* __restrict__ A,
                                                     const ushort_t* __restrict__ B,
                                                     const float* __restrict__ ve,
                                                     const float* __restrict__ lam,
                                                     const float* __restrict__ cost,
                                                     const float* __restrict__ sint,
                                                     ushort_t* __restrict__ qb,
                                                     ushort_t* __restrict__ kbuf,
                                                     ushort_t* __restrict__ vtb)
{
    const int K = 1024;
    __shared__ __align__(16) ushort_t As[2][128 * 32];
    __shared__ __align__(16) ushort_t Bs[2][64 * 32];
    const int tid = threadIdx.x;
    const int lane = tid & 63;
    const int w = tid >> 6;
    const int wr = w >> 1, wc = w & 1;
    const int l15 = lane & 15, hi = lane >> 4;
    const int m0 = blockIdx.y * 128, n0 = blockIdx.x * 64;
    const int sec = n0 >> 10;                       // 0=q 1=k 2=v
    const int h = ((n0 & 1023) >> 5) + wc;          // head for this wave's quadrant
    const int srow = lane >> 2, scol = (lane & 3) * 8;

    f32x4 acc[4][2] = {};

    auto stage = [&](int k0, int buf){
        #pragma unroll
        for (int i = 0; i < 2; ++i){
            int c = w + i * 4;
            gld16(&A[(size_t)(m0 + c * 16 + srow) * K + k0 + scol], &As[buf][c * 512]);
        }
        gld16(&B[(size_t)(n0 + w * 16 + srow) * K + k0 + scol], &Bs[buf][w * 512]);
    };

    stage(0, 0);
    int cur = 0;
    for (int k0 = 0; k0 < K; k0 += 32){
        __syncthreads();
        if (k0 + 32 < K) stage(k0 + 32, cur ^ 1);
        bf16x8 af[4], bfr[2];
        #pragma unroll
        for (int mi = 0; mi < 4; ++mi)
            af[mi] = *(const bf16x8*)&As[cur][(wr * 64 + mi * 16 + l15) * 32 + hi * 8];
        #pragma unroll
        for (int ni = 0; ni < 2; ++ni)
            bfr[ni] = *(const bf16x8*)&Bs[cur][(wc * 32 + ni * 16 + l15) * 32 + hi * 8];
        #pragma unroll
        for (int mi = 0; mi < 4; ++mi)
            #pragma unroll
            for (int ni = 0; ni < 2; ++ni)
                acc[mi][ni] = __builtin_amdgcn_mfma_f32_16x16x32_bf16(af[mi], bfr[ni], acc[mi][ni], 0, 0, 0);
        cur ^= 1;
    }

    // ---------- fused epilogue ----------
    if (sec < 2){
        ushort_t* dst = (sec == 0) ? qb : kbuf;
        const float qscl = (sec == 0) ? SCALE_ * LOG2E_ : 1.0f;
        #pragma unroll
        for (int mi = 0; mi < 4; ++mi){
            #pragma unroll
            for (int r = 0; r < 4; ++r){
                const int t = m0 + wr * 64 + mi * 16 + hi * 4 + r;
                float v0 = acc[mi][0][r], v1 = acc[mi][1][r];
                float ss = v0 * v0 + v1 * v1;
                ss += __shfl_xor(ss, 1);
                ss += __shfl_xor(ss, 2);
                ss += __shfl_xor(ss, 4);
                ss += __shfl_xor(ss, 8);
                const float inv = rsqrtf(ss * (1.0f / 32.0f) + RMS_EPS_);
                const float c = cost[t * 16 + l15], s = sint[t * 16 + l15];
                const float n0v = v0 * inv, n1v = v1 * inv;
                const float o0 = (n0v * c + n1v * s) * qscl;
                const float o1 = (n1v * c - n0v * s) * qscl;
                size_t base = ((size_t)h * TSEQ + t) * 32;
                dst[base + l15]      = f2bfn(o0);
                dst[base + 16 + l15] = f2bfn(o1);
            }
        }
    } else {
        const float l0 = lam[0], l1 = lam[1];
        __syncthreads();
        ushort_t* vt = &As[0][0] + w * 2048;
        #pragma unroll
        for (int ni = 0; ni < 2; ++ni){
            const int d = ni * 16 + l15;
            #pragma unroll
            for (int mi = 0; mi < 4; ++mi){
                #pragma unroll
                for (int r = 0; r < 4; ++r){
                    const int t = m0 + wr * 64 + mi * 16 + hi * 4 + r;
                    const int tl = mi * 16 + hi * 4 + r;
                    float vef = ve[(size_t)t * 1024 + h * 32 + d];
                    float ov = l0 * acc[mi][ni][r] + l1 * vef;
                    const int g = (tl >> 3) ^ (d & 7);
                    vt[d * 64 + g * 8 + (tl & 7)] = f2bfn(ov);
                }
            }
        }
        __syncthreads();
        const int tc = lane & 7;
        #pragma unroll
        for (int p = 0; p < 4; ++p){
            const int d = p * 8 + (lane >> 3);
            const int g = tc ^ (d & 7);
            u16x8 o = *(const u16x8*)&vt[d * 64 + g * 8];
            *(u16x8*)&vtb[((size_t)h * HD_ + d) * TSEQ + m0 + wr * 64 + tc * 8] = o;
        }
    }
}

// ---------------- out-proj GEMM: 64x64, BK=64, double-buffered ----------------
__global__ __launch_bounds__(256) void k_gemm_out(const ushort_t* __restrict__ A,
                                                  const ushort_t* __restrict__ B,
                                                  float* __restrict__ C,
                                                  int M, int N, int K)
{
    __shared__ __align__(16) ushort_t As[2][64 * 64];
    __shared__ __align__(16) ushort_t Bs[2][64 * 64];
    const int tid = threadIdx.x;
    const int lane = tid & 63;
    const int w = tid >> 6;
    const int wr = w >> 1, wc = w & 1;
    const int l15 = lane & 15, hi = lane >> 4;
    const int m0 = blockIdx.y * 64, n0 = blockIdx.x * 64;
    const int srow = lane >> 3, scol = (lane & 7) * 8;

    f32x4 acc[2][2] = {};

    auto stage = [&](int k0, int buf){
        #pragma unroll
        for (int i = 0; i < 2; ++i){
            int c = w * 2 + i;
            gld16(&A[(size_t)(m0 + c * 8 + srow) * K + k0 + scol], &As[buf][c * 512]);
            gld16(&B[(size_t)(n0 + c * 8 + srow) * K + k0 + scol], &Bs[buf][c * 512]);
        }
    };

    stage(0, 0);
    int cur = 0;
    for (int k0 = 0; k0 < K; k0 += 64){
        __syncthreads();
        if (k0 + 64 < K) stage(k0 + 64, cur ^ 1);
        bf16x8 af[2][2], bfr[2][2];
        #pragma unroll
        for (int mi = 0; mi < 2; ++mi)
            #pragma unroll
            for (int sub = 0; sub < 2; ++sub)
                af[mi][sub] = *(const bf16x8*)&As[cur][(wr * 32 + mi * 16 + l15) * 64 + sub * 32 + hi * 8];
        #pragma unroll
        for (int ni = 0; ni < 2; ++ni)
            #pragma unroll
            for (int sub = 0; sub < 2; ++sub)
                bfr[ni][sub] = *(const bf16x8*)&Bs[cur][(wc * 32 + ni * 16 + l15) * 64 + sub * 32 + hi * 8];
        #pragma unroll
        for (int sub = 0; sub < 2; ++sub)
            #pragma unroll
            for (int mi = 0; mi < 2; ++mi)
                #pragma unroll
                for (int ni = 0; ni < 2; ++ni)
                    acc[mi][ni] = __builtin_amdgcn_mfma_f32_16x16x32_bf16(af[mi][sub], bfr[ni][sub], acc[mi][ni], 0, 0, 0);
        cur ^= 1;
    }

    #pragma unroll
    for (int mi = 0; mi < 2; ++mi)
        #pragma unroll
        for (int ni = 0; ni < 2; ++ni)
            #pragma unroll
            for (int r = 0; r < 4; ++r){
                int row = m0 + wr * 32 + mi * 16 + hi * 4 + r;
                int col = n0 + wc * 32 + ni * 16 + l15;
                C[(size_t)row * N + col] = acc[mi][ni][r];
            }
}

// ---------------- causal flash attention, 1 q-tile/block, KVBLK=64 dbuf ----------------
// No-max softmax: ||q||=||k||=sqrt(32), SCALE*log2e folded into q -> |s|<=5.6 -> P=exp2(s) raw.
template<bool MASK>
__device__ __forceinline__ void chain_step(const bf16x8* kf, const bf16x8* vv0, const bf16x8* vv1,
                                           ushort_t* pb, const bf16x8& qf,
                                           int kb0, int qrow, int l15, int hi,
                                           f32x4& a0, f32x4& a1, float& lp)
{
    f32x4 s[4];
    __builtin_amdgcn_s_setprio(1);
    #pragma unroll
    for (int ni = 0; ni < 4; ++ni){
        f32x4 z = {0.f, 0.f, 0.f, 0.f};
        s[ni] = __builtin_amdgcn_mfma_f32_16x16x32_bf16(kf[ni], qf, z, 0, 0, 0);  // S^T
    }
    __builtin_amdgcn_s_setprio(0);
    if (MASK){
        const int relc = qrow - kb0 - 4 * hi;
        #pragma unroll
        for (int ni = 0; ni < 4; ++ni)
            #pragma unroll
            for (int r = 0; r < 4; ++r)
                if (16 * ni + r > relc) s[ni][r] = -1e30f;
    }
    float ps = 0.f;
    #pragma unroll
    for (int ni = 0; ni < 4; ++ni)
        #pragma unroll
        for (int r = 0; r < 4; ++r){
            float p = fexp2(s[ni][r]);
            s[ni][r] = p;
            ps += p;
        }
    lp += ps;
    #pragma unroll
    for (int ni = 0; ni < 4; ++ni){
        ushort4 pk;
        pk.x = f2bfn(s[ni][0]); pk.y = f2bfn(s[ni][1]);
        pk.z = f2bfn(s[ni][2]); pk.w = f2bfn(s[ni][3]);
        *(ushort4*)&pb[l15 * 72 + ni * 16 + hi * 4] = pk;
    }
    __builtin_amdgcn_s_setprio(1);
    #pragma unroll
    for (int kk = 0; kk < 2; ++kk){
        bf16x8 pf = *(const bf16x8*)&pb[l15 * 72 + kk * 32 + hi * 8];
        a0 = __builtin_amdgcn_mfma_f32_16x16x32_bf16(vv0[kk], pf, a0, 0, 0, 0);
        a1 = __builtin_amdgcn_mfma_f32_16x16x32_bf16(vv1[kk], pf, a1, 0, 0, 0);
    }
    __builtin_amdgcn_s_setprio(0);
}

// grid 1024 = 8 XCDs x (32 q-tiles x 4 heads). xcd=bid&7 -> heads [4*xcd,4*xcd+4).
// Heavy-first: qt descends with idx so the longest chains start earliest.
// 4 blocks/CU (LDS 25.6KB, launch_bounds(256,4)) -> 16 waves/CU for latency hiding.
__global__ __launch_bounds__(256, 4) void k_attn(const ushort_t* __restrict__ qb,
                                                 const ushort_t* __restrict__ kb,
                                                 const ushort_t* __restrict__ vtb,
                                                 ushort_t* __restrict__ yb)
{
    const int bid = blockIdx.x;
    const int xcd = bid & 7, idx = bid >> 3;
    const int h  = xcd * 4 + (idx & 3);
    const int qt = 31 - (idx >> 2);
    const int tid = threadIdx.x;
    const int w = tid >> 6, lane = tid & 63;
    const int l15 = lane & 15, hi = lane >> 4;

    __shared__ __align__(16) ushort_t Kbuf[2][64 * 32];   // [key][d], 64B rows
    __shared__ __align__(16) ushort_t Vbuf[2][32 * 64];   // [d][key], 128B rows, slot-XOR swz
    __shared__ __align__(16) ushort_t Pbuf[4][16 * 72];

    const ushort_t* kb_h = kb + (size_t)h * TSEQ * HD_;
    const ushort_t* vt_h = vtb + (size_t)h * HD_ * TSEQ;
    const ushort_t* qb_h = qb + (size_t)h * TSEQ * HD_;

    const int qw = qt * 64 + w * 16;
    const bf16x8 qf = *(const bf16x8*)&qb_h[(size_t)(qw + l15) * 32 + hi * 8];

    // staging: wave w stages K rows 16w..16w+15 and V d-rows 8w..8w+7 (linear LDS dest)
    const int krow = w * 16 + (lane >> 2);
    const int kcol = (lane & 3) * 8;
    const int vrow = w * 8 + (lane >> 3);
    const int vslot = (lane & 7) ^ (vrow & 7);            // pre-swizzled source
    auto stage = [&](int kt, int buf){
        const int kb0 = kt * 64;
        gld16(&kb_h[(size_t)(kb0 + krow) * 32 + kcol], &Kbuf[buf][w * 512]);
        gld16(&vt_h[(size_t)vrow * TSEQ + kb0 + vslot * 8], &Vbuf[buf][w * 512]);
    };

    f32x4 a0 = {0.f,0.f,0.f,0.f}, a1 = a0;
    float lp = 0.f;
    ushort_t* pb = &Pbuf[w][0];

    const int nT = qt + 1;
    stage(0, 0);
    int cur = 0;
    for (int kt = 0; kt < nT; ++kt){
        __syncthreads();                        // drains stage vmcnt + all lgkm
        if (kt + 1 < nT) stage(kt + 1, cur ^ 1);
        const int kb0 = kt * 64;
        bf16x8 kf[4], vv0[2], vv1[2];
        #pragma unroll
        for (int ni = 0; ni < 4; ++ni)
            kf[ni] = *(const bf16x8*)&Kbuf[cur][(ni * 16 + l15) * 32 + hi * 8];
        #pragma unroll
        for (int kk = 0; kk < 2; ++kk){
            int sl = kk * 4 + hi;
            vv0[kk] = *(const bf16x8*)&Vbuf[cur][l15 * 64 + (sl ^ (l15 & 7)) * 8];
            vv1[kk] = *(const bf16x8*)&Vbuf[cur][(16 + l15) * 64 + (sl ^ (l15 & 7)) * 8];
        }
        if (kt < qt)
            chain_step<false>(kf, vv0, vv1, pb, qf, kb0, qw + l15, l15, hi, a0, a1, lp);
        else
            chain_step<true >(kf, vv0, vv1, pb, qf, kb0, qw + l15, l15, hi, a0, a1, lp);
        cur ^= 1;
    }

    lp += __shfl_xor(lp, 16);
    lp += __shfl_xor(lp, 32);
    float inv = 1.0f / lp;
    ushort4 o0, o1;
    o0.x = f2bfn(a0[0]*inv); o0.y = f2bfn(a0[1]*inv);
    o0.z = f2bfn(a0[2]*inv); o0.w = f2bfn(a0[3]*inv);
    o1.x = f2bfn(a1[0]*inv); o1.y = f2bfn(a1[1]*inv);
    o1.z = f2bfn(a1[2]*inv); o1.w = f2bfn(a1[3]*inv);
    size_t base = (size_t)(qw + l15) * 1024 + h * 32;
    *(ushort4*)&yb[base + hi * 4]      = o0;
    *(ushort4*)&yb[base + 16 + hi * 4] = o1;
}

// ---------------- launcher ----------------
extern "C" void kernel_launch(void* const* d_in, const int* in_sizes, int n_in,
                              void* d_out, int out_size, void* d_ws, size_t ws_size,
                              hipStream_t stream)
{
    const float* x   = (const float*)d_in[0];
    const float* ve  = (const float*)d_in[1];
    const float* qkw = (const float*)d_in[2];
    const float* lam = (const float*)d_in[3];
    const float* cpw = (const float*)d_in[4];

    char* ws = (char*)d_ws;
    size_t o = 0;
    auto take = [&](size_t bytes) -> char* {
        char* p = ws + o; o += (bytes + 255) & ~(size_t)255; return p;
    };
    ushort_t* xb   = (ushort_t*)take((size_t)TSEQ * 1024 * 2);
    ushort_t* wb   = (ushort_t*)take((size_t)3072 * 1024 * 2);
    ushort_t* cpb  = (ushort_t*)take((size_t)1024 * 1024 * 2);
    float*    cost = (float*)take((size_t)TSEQ * 16 * 4);
    float*    sint = (float*)take((size_t)TSEQ * 16 * 4);
    ushort_t* qb   = (ushort_t*)take((size_t)NHEADS * TSEQ * HD_ * 2);
    ushort_t* kb   = (ushort_t*)take((size_t)NHEADS * TSEQ * HD_ * 2 + 8192);
    ushort_t* vtb  = (ushort_t*)take((size_t)NHEADS * HD_ * TSEQ * 2 + 8192);
    ushort_t* yb   = xb;  // xb dead after QKV GEMM; reuse for y

    const int prep_items = (TSEQ * 1024 + 3 * 1024 * 1024 + 1024 * 1024) / 4 + TSEQ * 16;
    k_prep<<<(prep_items + 255) / 256, 256, 0, stream>>>(x, qkw, cpw, xb, wb, cpb, cost, sint);
    k_gemm_qkv<<<dim3(48, 16), 256, 0, stream>>>(xb, wb, ve, lam, cost, sint, qb, kb, vtb);
    k_attn<<<1024, 256, 0, stream>>>(qb, kb, vtb, yb);
    k_gemm_out<<<dim3(1024 / 64, TSEQ / 64), 256, 0, stream>>>(yb, cpb, (float*)d_out, TSEQ, 1024, 1024);
}